// Round 1
// baseline (7148.586 us; speedup 1.0000x reference)
//
#include <hip/hip_runtime.h>

#define N_NODES 100000
#define N_EDGES 1600000
#define N_GRAPHS 256
#define HID 128
#define BN_EPS 1e-5f

typedef __bf16 bf16x8 __attribute__((ext_vector_type(8)));
typedef float f32x4 __attribute__((ext_vector_type(4)));

// ---------------- weight prep: W (K x 128 row-major) -> Wt bf16 (128 x K) ----
__global__ __launch_bounds__(256) void prep_w_kernel(const float* __restrict__ w,
                                                     __bf16* __restrict__ wt, int K) {
  int idx = blockIdx.x * 256 + threadIdx.x;
  if (idx >= 128 * K) return;
  int n = idx / K, k = idx - n * K;
  wt[idx] = (__bf16)w[k * 128 + n];
}

// ---------------- edge scatter-add: agg[dst] += h[src] ----------------------
template <int CIN>
__global__ __launch_bounds__(256) void scatter_kernel(const float* __restrict__ h,
                                                      const int* __restrict__ ei,
                                                      float* __restrict__ agg) {
  constexpr int C4 = CIN / 4;
  int tid = blockIdx.x * 256 + threadIdx.x;
  if (tid >= N_EDGES * C4) return;
  int e = tid / C4, c = tid - (tid / C4) * C4;
  int src = ei[e], dst = ei[N_EDGES + e];
  const float4 v = *(const float4*)(h + (size_t)src * CIN + c * 4);
  float* o = agg + (size_t)dst * CIN + c * 4;
  atomicAdd(o + 0, v.x);
  atomicAdd(o + 1, v.y);
  atomicAdd(o + 2, v.z);
  atomicAdd(o + 3, v.w);
}

// ---------------- fused MLP: u = relu((in+agg)@W1+b1)@W2+b2 + BN partials ---
template <int CIN>
__global__ __launch_bounds__(256) void fused_mlp_kernel(
    const float* __restrict__ in, const float* __restrict__ agg,
    const __bf16* __restrict__ w1t, const float* __restrict__ b1,
    const __bf16* __restrict__ w2t, const float* __restrict__ b2,
    float* __restrict__ u, float* __restrict__ bnstats) {
  constexpr int ZS = CIN + 8;   // bf16 elems/row (+pad)
  constexpr int TS = HID + 8;   // bf16 elems/row (+pad)
  constexpr int US = 132;       // fp32 elems/row (+pad)
  constexpr int ZB = 64 * ZS * 2;
  constexpr int TB = 64 * TS * 2;
  constexpr int UB = 64 * US * 4;
  constexpr int SB = (ZB + TB) > UB ? (ZB + TB) : UB;
  __shared__ __align__(16) char smem[SB];
  __bf16* zt = (__bf16*)smem;
  __bf16* tt = (__bf16*)(smem + ZB);

  const int t = threadIdx.x;
  const int wave = t >> 6;
  const int lane = t & 63;
  const int l16 = lane & 15;
  const int quad = lane >> 4;
  const int rowbase = blockIdx.x * 64;
  const int nvalid = min(64, N_NODES - rowbase);

  // Phase A: z = in + agg  -> LDS (bf16)
  {
    constexpr int C4 = CIN / 4;
    for (int f = t; f < 64 * C4; f += 256) {
      int r = f / C4, c4 = f - r * C4;
      float4 v = {0.f, 0.f, 0.f, 0.f};
      int gr = rowbase + r;
      if (gr < N_NODES) {
        float4 a = *(const float4*)(in + (size_t)gr * CIN + c4 * 4);
        float4 g = *(const float4*)(agg + (size_t)gr * CIN + c4 * 4);
        v.x = a.x + g.x; v.y = a.y + g.y; v.z = a.z + g.z; v.w = a.w + g.w;
      }
      __bf16* p = zt + r * ZS + c4 * 4;
      p[0] = (__bf16)v.x; p[1] = (__bf16)v.y; p[2] = (__bf16)v.z; p[3] = (__bf16)v.w;
    }
  }
  __syncthreads();

  const f32x4 zero4 = {0.f, 0.f, 0.f, 0.f};
  f32x4 acc[8];

  // Phase B: t = relu(z @ W1 + b1) -> LDS (bf16)
  {
#pragma unroll
    for (int ct = 0; ct < 8; ct++) acc[ct] = zero4;
    const __bf16* arow = zt + (wave * 16 + l16) * ZS + quad * 8;
#pragma unroll
    for (int ks = 0; ks < CIN / 32; ks++) {
      bf16x8 af = *(const bf16x8*)(arow + ks * 32);
#pragma unroll
      for (int ct = 0; ct < 8; ct++) {
        bf16x8 bfr = *(const bf16x8*)(w1t + (ct * 16 + l16) * CIN + ks * 32 + quad * 8);
        acc[ct] = __builtin_amdgcn_mfma_f32_16x16x32_bf16(af, bfr, acc[ct], 0, 0, 0);
      }
    }
#pragma unroll
    for (int ct = 0; ct < 8; ct++) {
      int col = ct * 16 + l16;
      float bias = b1[col];
#pragma unroll
      for (int r = 0; r < 4; r++) {
        float v = acc[ct][r] + bias;
        tt[(wave * 16 + quad * 4 + r) * TS + col] = (__bf16)(v > 0.f ? v : 0.f);
      }
    }
  }
  __syncthreads();

  // Phase C: u = t @ W2 + b2
  {
#pragma unroll
    for (int ct = 0; ct < 8; ct++) acc[ct] = zero4;
    const __bf16* arow = tt + (wave * 16 + l16) * TS + quad * 8;
#pragma unroll
    for (int ks = 0; ks < HID / 32; ks++) {
      bf16x8 af = *(const bf16x8*)(arow + ks * 32);
#pragma unroll
      for (int ct = 0; ct < 8; ct++) {
        bf16x8 bfr = *(const bf16x8*)(w2t + (ct * 16 + l16) * HID + ks * 32 + quad * 8);
        acc[ct] = __builtin_amdgcn_mfma_f32_16x16x32_bf16(af, bfr, acc[ct], 0, 0, 0);
      }
    }
  }
  __syncthreads();  // all tt reads done; reuse smem as fp32 u tile
  float* uo = (float*)smem;
#pragma unroll
  for (int ct = 0; ct < 8; ct++) {
    int col = ct * 16 + l16;
    float bias = b2[col];
#pragma unroll
    for (int r = 0; r < 4; r++) {
      uo[(wave * 16 + quad * 4 + r) * US + col] = acc[ct][r] + bias;
    }
  }
  __syncthreads();

  // coalesced global store of u + per-block BN partial sums
  for (int f = t; f < 64 * 32; f += 256) {
    int r = f >> 5, c4 = f & 31;
    if (r < nvalid) {
      f32x4 v = *(const f32x4*)(uo + r * US + c4 * 4);
      *(f32x4*)(u + (size_t)(rowbase + r) * HID + c4 * 4) = v;
    }
  }
  if (t < HID) {
    float s = 0.f, sq = 0.f;
    for (int r = 0; r < nvalid; r++) {
      float v = uo[r * US + t];
      s += v;
      sq += v * v;
    }
    atomicAdd(&bnstats[t], s);
    atomicAdd(&bnstats[HID + t], sq);
  }
}

// ---------------- BN finalize: a = g*rsqrt(var+eps), b = beta - mean*a ------
__global__ __launch_bounds__(128) void bn_finalize_kernel(const float* __restrict__ bnstats,
                                                          const float* __restrict__ gamma,
                                                          const float* __restrict__ beta,
                                                          float* __restrict__ bnab) {
  int t = threadIdx.x;
  const float invN = 1.f / (float)N_NODES;
  float mean = bnstats[t] * invN;
  float var = bnstats[HID + t] * invN - mean * mean;
  float a = gamma[t] * rsqrtf(var + BN_EPS);
  bnab[t] = a;
  bnab[HID + t] = beta[t] - mean * a;
}

// ---------------- BN apply (+relu), in-place, layers 0-1 --------------------
__global__ __launch_bounds__(256) void bn_apply_kernel(float* __restrict__ u,
                                                       const float* __restrict__ bnab) {
  int idx = blockIdx.x * 256 + threadIdx.x;
  if (idx >= N_NODES * 32) return;
  int c4 = idx & 31;
  f32x4 v = ((const f32x4*)u)[idx];
  f32x4 a = ((const f32x4*)bnab)[c4];
  f32x4 b = ((const f32x4*)bnab)[32 + c4];
#pragma unroll
  for (int i = 0; i < 4; i++) {
    float x = v[i] * a[i] + b[i];
    v[i] = x > 0.f ? x : 0.f;
  }
  ((f32x4*)u)[idx] = v;
}

// ---------------- BN apply + mean-pool accumulate (layer 2) -----------------
__global__ __launch_bounds__(128) void bn_apply_pool_kernel(const float* __restrict__ u,
                                                            const float* __restrict__ bnab,
                                                            const int* __restrict__ batch,
                                                            float* __restrict__ pool) {
  int c = threadIdx.x;  // feature column
  int r0 = blockIdx.x * 64;
  if (r0 >= N_NODES) return;
  int rend = min(r0 + 64, N_NODES);
  float a = bnab[c], b = bnab[HID + c];
  float accv = 0.f;
  int curg = -1;
  for (int r = r0; r < rend; r++) {
    int g = batch[r];
    if (g != curg) {
      if (curg >= 0) atomicAdd(&pool[curg * HID + c], accv);
      curg = g;
      accv = 0.f;
    }
    float v = u[(size_t)r * HID + c];
    v = v * a + b;
    accv += (v > 0.f ? v : 0.f);
  }
  if (curg >= 0) atomicAdd(&pool[curg * HID + c], accv);
}

// ---------------- per-graph node counts (batch is sorted) -------------------
__global__ __launch_bounds__(256) void count_kernel(const int* __restrict__ batch,
                                                    int* __restrict__ counts) {
  int t = blockIdx.x * 256 + threadIdx.x;
  int r0 = t * 64;
  if (r0 >= N_NODES) return;
  int rend = min(r0 + 64, N_NODES);
  int curg = batch[r0], cnt = 0;
  for (int r = r0; r < rend; r++) {
    int g = batch[r];
    if (g != curg) {
      atomicAdd(&counts[curg], cnt);
      curg = g;
      cnt = 1;
    } else {
      cnt++;
    }
  }
  atomicAdd(&counts[curg], cnt);
}

// ---------------- hg = pool/cnt; out = hg @ proj_w + proj_b -----------------
__global__ __launch_bounds__(128) void pool_proj_kernel(const float* __restrict__ pool,
                                                        const int* __restrict__ counts,
                                                        const float* __restrict__ pw,
                                                        const float* __restrict__ pb,
                                                        float* __restrict__ out) {
  int g = blockIdx.x;
  int c = threadIdx.x;
  __shared__ float hg[HID];
  float cnt = (float)max(counts[g], 1);
  hg[c] = pool[g * HID + c] / cnt;
  __syncthreads();
  float acc = pb[c];
#pragma unroll 8
  for (int k = 0; k < HID; k++) acc += hg[k] * pw[k * HID + c];
  out[g * HID + c] = acc;
}

// ============================================================================
extern "C" void kernel_launch(void* const* d_in, const int* in_sizes, int n_in,
                              void* d_out, int out_size, void* d_ws, size_t ws_size,
                              hipStream_t stream) {
  (void)in_sizes; (void)n_in; (void)out_size; (void)ws_size;
  const float* x = (const float*)d_in[0];
  const int* ei = (const int*)d_in[1];
  const int* batch = (const int*)d_in[2];
  const float* w1[3] = {(const float*)d_in[3], (const float*)d_in[9], (const float*)d_in[15]};
  const float* b1[3] = {(const float*)d_in[4], (const float*)d_in[10], (const float*)d_in[16]};
  const float* w2[3] = {(const float*)d_in[5], (const float*)d_in[11], (const float*)d_in[17]};
  const float* b2[3] = {(const float*)d_in[6], (const float*)d_in[12], (const float*)d_in[18]};
  const float* gm[3] = {(const float*)d_in[7], (const float*)d_in[13], (const float*)d_in[19]};
  const float* bt[3] = {(const float*)d_in[8], (const float*)d_in[14], (const float*)d_in[20]};
  const float* pw = (const float*)d_in[21];
  const float* pb = (const float*)d_in[22];
  float* out = (float*)d_out;

  // workspace carve
  char* ws = (char*)d_ws;
  float* hA = (float*)ws;            ws += (size_t)N_NODES * HID * 4;   // 51.2 MB
  float* agg = (float*)ws;           ws += (size_t)N_NODES * HID * 4;   // 51.2 MB
  __bf16* w1t0 = (__bf16*)ws;        ws += 128 * 64 * 2;
  __bf16* w2t0 = (__bf16*)ws;        ws += 128 * 128 * 2;
  __bf16* w1t1 = (__bf16*)ws;        ws += 128 * 128 * 2;
  __bf16* w2t1 = (__bf16*)ws;        ws += 128 * 128 * 2;
  __bf16* w1t2 = (__bf16*)ws;        ws += 128 * 128 * 2;
  __bf16* w2t2 = (__bf16*)ws;        ws += 128 * 128 * 2;
  float* bnstats = (float*)ws;       ws += 256 * 4;
  float* bnab = (float*)ws;          ws += 256 * 4;
  float* pool = (float*)ws;          ws += N_GRAPHS * HID * 4;          // contiguous with counts
  int* counts = (int*)ws;            ws += N_GRAPHS * 4;

  __bf16* w1t[3] = {w1t0, w1t1, w1t2};
  __bf16* w2t[3] = {w2t0, w2t1, w2t2};

  // weight prep (bf16 transposed)
  prep_w_kernel<<<(128 * 64 + 255) / 256, 256, 0, stream>>>(w1[0], w1t0, 64);
  prep_w_kernel<<<(128 * 128 + 255) / 256, 256, 0, stream>>>(w2[0], w2t0, 128);
  prep_w_kernel<<<(128 * 128 + 255) / 256, 256, 0, stream>>>(w1[1], w1t1, 128);
  prep_w_kernel<<<(128 * 128 + 255) / 256, 256, 0, stream>>>(w2[1], w2t1, 128);
  prep_w_kernel<<<(128 * 128 + 255) / 256, 256, 0, stream>>>(w1[2], w1t2, 128);
  prep_w_kernel<<<(128 * 128 + 255) / 256, 256, 0, stream>>>(w2[2], w2t2, 128);

  // zero pool + counts (contiguous), count nodes/graph
  hipMemsetAsync(pool, 0, (size_t)N_GRAPHS * HID * 4 + N_GRAPHS * 4, stream);
  count_kernel<<<((N_NODES + 63) / 64 + 255) / 256, 256, 0, stream>>>(batch, counts);

  const int mlp_blocks = (N_NODES + 63) / 64;  // 1563

  for (int l = 0; l < 3; l++) {
    const float* in = (l == 0) ? x : hA;
    if (l == 0) {
      hipMemsetAsync(agg, 0, (size_t)N_NODES * 64 * 4, stream);
      scatter_kernel<64><<<(N_EDGES * 16 + 255) / 256, 256, 0, stream>>>(in, ei, agg);
    } else {
      hipMemsetAsync(agg, 0, (size_t)N_NODES * 128 * 4, stream);
      scatter_kernel<128><<<(N_EDGES * 32 + 255) / 256, 256, 0, stream>>>(in, ei, agg);
    }
    hipMemsetAsync(bnstats, 0, 256 * 4, stream);
    if (l == 0) {
      fused_mlp_kernel<64><<<mlp_blocks, 256, 0, stream>>>(in, agg, w1t[l], b1[l], w2t[l], b2[l], hA, bnstats);
    } else {
      fused_mlp_kernel<128><<<mlp_blocks, 256, 0, stream>>>(in, agg, w1t[l], b1[l], w2t[l], b2[l], hA, bnstats);
    }
    bn_finalize_kernel<<<1, 128, 0, stream>>>(bnstats, gm[l], bt[l], bnab);
    if (l < 2) {
      bn_apply_kernel<<<(N_NODES * 32 + 255) / 256, 256, 0, stream>>>(hA, bnab);
    } else {
      bn_apply_pool_kernel<<<mlp_blocks, 128, 0, stream>>>(hA, bnab, batch, pool);
    }
  }

  pool_proj_kernel<<<N_GRAPHS, 128, 0, stream>>>(pool, counts, pw, pb, out);
}

// Round 3
// 1220.366 us; speedup vs baseline: 5.8577x; 5.8577x over previous
//
#include <hip/hip_runtime.h>

#define N_NODES 100000
#define N_EDGES 1600000
#define N_GRAPHS 256
#define HID 128
#define BN_EPS 1e-5f

typedef __bf16 bf16x8 __attribute__((ext_vector_type(8)));
typedef __bf16 bf16x4 __attribute__((ext_vector_type(4)));
typedef __bf16 bf16x2 __attribute__((ext_vector_type(2)));
typedef float f32x4 __attribute__((ext_vector_type(4)));

// ---------------- weight prep: W (K x 128 row-major) -> Wt bf16 (128 x K) ----
__global__ __launch_bounds__(256) void prep_w_kernel(const float* __restrict__ w,
                                                     __bf16* __restrict__ wt, int K) {
  int idx = blockIdx.x * 256 + threadIdx.x;
  if (idx >= 128 * K) return;
  int n = idx / K, k = idx - n * K;
  wt[idx] = (__bf16)w[k * 128 + n];
}

// ---------------- CSR build: histogram of dst ------------------------------
__global__ __launch_bounds__(256) void hist_kernel(const int* __restrict__ ei,
                                                   int* __restrict__ counts) {
  int e = blockIdx.x * 256 + threadIdx.x;
  if (e < N_EDGES) atomicAdd(&counts[ei[N_EDGES + e]], 1);
}

// ---------------- CSR build: single-block exclusive scan --------------------
__global__ __launch_bounds__(1024) void scan_kernel(const int* __restrict__ counts,
                                                    int* __restrict__ starts,
                                                    int* __restrict__ cursor) {
  __shared__ int ps[1024];
  int t = threadIdx.x;
  const int CH = (N_NODES + 1023) / 1024;  // 98
  int lo = t * CH, hi = min(lo + CH, N_NODES);
  int s = 0;
  for (int i = lo; i < hi; i++) s += counts[i];
  ps[t] = s;
  __syncthreads();
  for (int off = 1; off < 1024; off <<= 1) {
    int v = ps[t];
    int u = (t >= off) ? ps[t - off] : 0;
    __syncthreads();
    ps[t] = v + u;
    __syncthreads();
  }
  int base = (t == 0) ? 0 : ps[t - 1];
  for (int i = lo; i < hi; i++) {
    starts[i] = base;
    cursor[i] = base;
    base += counts[i];
  }
  if (t == 1023) starts[N_NODES] = ps[1023];
}

// ---------------- CSR build: reorder src by dst bucket ----------------------
__global__ __launch_bounds__(256) void reorder_kernel(const int* __restrict__ ei,
                                                      int* __restrict__ cursor,
                                                      int* __restrict__ srcs) {
  int e = blockIdx.x * 256 + threadIdx.x;
  if (e >= N_EDGES) return;
  int dst = ei[N_EDGES + e];
  int pos = atomicAdd(&cursor[dst], 1);
  srcs[pos] = ei[e];
}

// ---------------- fused gather + MLP ----------------------------------------
// CIN==64: in_ is fp32 x (no BN).  CIN==128: in_ is bf16 pre-BN u of prev layer.
// h = DOBN ? relu(a*in+b) : in ; z_row = h_row + sum_{CSR[row]} h_src
// u = relu(z @ W1 + b1) @ W2 + b2  (stored bf16); BN partial sums from fp32.
template <int CIN, bool DOBN>
__global__ __launch_bounds__(256) void fused_mlp_kernel(
    const void* __restrict__ in_, const int* __restrict__ starts,
    const int* __restrict__ srcs, const float* __restrict__ bnab,
    const __bf16* __restrict__ w1t, const float* __restrict__ b1,
    const __bf16* __restrict__ w2t, const float* __restrict__ b2,
    __bf16* __restrict__ u, float* __restrict__ bnstats) {
  constexpr int ZS = CIN + 8;   // bf16 elems/row (+pad)
  constexpr int TS = HID + 8;   // bf16 elems/row (+pad)
  constexpr int US = 132;       // fp32 elems/row (+pad)
  constexpr int ZB = 64 * ZS * 2;
  constexpr int TB = 64 * TS * 2;
  constexpr int UB = 64 * US * 4;
  constexpr int SB = (ZB + TB) > UB ? (ZB + TB) : UB;
  __shared__ __align__(16) char smem[SB];
  __bf16* zt = (__bf16*)smem;
  __bf16* tt = (__bf16*)(smem + ZB);

  const int t = threadIdx.x;
  const int wave = t >> 6;
  const int lane = t & 63;
  const int l16 = lane & 15;
  const int quad = lane >> 4;
  const int rowbase = blockIdx.x * 64;
  const int nvalid = min(64, N_NODES - rowbase);

  // Phase A: gather-aggregate (+BN/relu of input), z -> LDS (bf16)
  if constexpr (CIN == 64) {
    const float* in = (const float*)in_;
    for (int r = wave; r < 64; r += 4) {
      int gr = rowbase + r;
      float acc = 0.f;
      if (gr < N_NODES) {
        acc = in[(size_t)gr * 64 + lane];
        int e = starts[gr], e1 = starts[gr + 1];
        for (; e + 3 < e1; e += 4) {
          int s0 = srcs[e], s1 = srcs[e + 1], s2 = srcs[e + 2], s3 = srcs[e + 3];
          float v0 = in[(size_t)s0 * 64 + lane];
          float v1 = in[(size_t)s1 * 64 + lane];
          float v2 = in[(size_t)s2 * 64 + lane];
          float v3 = in[(size_t)s3 * 64 + lane];
          acc += (v0 + v1) + (v2 + v3);
        }
        for (; e < e1; e++) acc += in[(size_t)srcs[e] * 64 + lane];
      }
      zt[r * ZS + lane] = (__bf16)acc;
    }
  } else {
    const __bf16* in = (const __bf16*)in_;
    float2 av = {1.f, 1.f}, bv = {0.f, 0.f};
    if (DOBN) {
      av = ((const float2*)bnab)[lane];
      bv = ((const float2*)(bnab + HID))[lane];
    }
    for (int r = wave; r < 64; r += 4) {
      int gr = rowbase + r;
      float ax = 0.f, ay = 0.f;
      if (gr < N_NODES) {
        bf16x2 v = *(const bf16x2*)(in + (size_t)gr * 128 + lane * 2);
        if (DOBN) {
          ax = fmaxf(fmaf(av.x, (float)v[0], bv.x), 0.f);
          ay = fmaxf(fmaf(av.y, (float)v[1], bv.y), 0.f);
        } else {
          ax = (float)v[0]; ay = (float)v[1];
        }
        int e = starts[gr], e1 = starts[gr + 1];
        for (; e + 3 < e1; e += 4) {
          int s0 = srcs[e], s1 = srcs[e + 1], s2 = srcs[e + 2], s3 = srcs[e + 3];
          bf16x2 v0 = *(const bf16x2*)(in + (size_t)s0 * 128 + lane * 2);
          bf16x2 v1 = *(const bf16x2*)(in + (size_t)s1 * 128 + lane * 2);
          bf16x2 v2 = *(const bf16x2*)(in + (size_t)s2 * 128 + lane * 2);
          bf16x2 v3 = *(const bf16x2*)(in + (size_t)s3 * 128 + lane * 2);
          if (DOBN) {
            ax += fmaxf(fmaf(av.x, (float)v0[0], bv.x), 0.f) + fmaxf(fmaf(av.x, (float)v1[0], bv.x), 0.f) +
                  fmaxf(fmaf(av.x, (float)v2[0], bv.x), 0.f) + fmaxf(fmaf(av.x, (float)v3[0], bv.x), 0.f);
            ay += fmaxf(fmaf(av.y, (float)v0[1], bv.y), 0.f) + fmaxf(fmaf(av.y, (float)v1[1], bv.y), 0.f) +
                  fmaxf(fmaf(av.y, (float)v2[1], bv.y), 0.f) + fmaxf(fmaf(av.y, (float)v3[1], bv.y), 0.f);
          } else {
            ax += ((float)v0[0] + (float)v1[0]) + ((float)v2[0] + (float)v3[0]);
            ay += ((float)v0[1] + (float)v1[1]) + ((float)v2[1] + (float)v3[1]);
          }
        }
        for (; e < e1; e++) {
          bf16x2 vv = *(const bf16x2*)(in + (size_t)srcs[e] * 128 + lane * 2);
          if (DOBN) {
            ax += fmaxf(fmaf(av.x, (float)vv[0], bv.x), 0.f);
            ay += fmaxf(fmaf(av.y, (float)vv[1], bv.y), 0.f);
          } else {
            ax += (float)vv[0]; ay += (float)vv[1];
          }
        }
      }
      bf16x2 z2 = {(__bf16)ax, (__bf16)ay};
      *(bf16x2*)(zt + r * ZS + lane * 2) = z2;
    }
  }
  __syncthreads();

  const f32x4 zero4 = {0.f, 0.f, 0.f, 0.f};
  f32x4 acc[8];

  // Phase B: t = relu(z @ W1 + b1) -> LDS (bf16)
  {
#pragma unroll
    for (int ct = 0; ct < 8; ct++) acc[ct] = zero4;
    const __bf16* arow = zt + (wave * 16 + l16) * ZS + quad * 8;
#pragma unroll
    for (int ks = 0; ks < CIN / 32; ks++) {
      bf16x8 af = *(const bf16x8*)(arow + ks * 32);
#pragma unroll
      for (int ct = 0; ct < 8; ct++) {
        bf16x8 bfr = *(const bf16x8*)(w1t + (ct * 16 + l16) * CIN + ks * 32 + quad * 8);
        acc[ct] = __builtin_amdgcn_mfma_f32_16x16x32_bf16(af, bfr, acc[ct], 0, 0, 0);
      }
    }
#pragma unroll
    for (int ct = 0; ct < 8; ct++) {
      int col = ct * 16 + l16;
      float bias = b1[col];
#pragma unroll
      for (int r = 0; r < 4; r++) {
        float v = acc[ct][r] + bias;
        tt[(wave * 16 + quad * 4 + r) * TS + col] = (__bf16)(v > 0.f ? v : 0.f);
      }
    }
  }
  __syncthreads();

  // Phase C: u = t @ W2 + b2
  {
#pragma unroll
    for (int ct = 0; ct < 8; ct++) acc[ct] = zero4;
    const __bf16* arow = tt + (wave * 16 + l16) * TS + quad * 8;
#pragma unroll
    for (int ks = 0; ks < HID / 32; ks++) {
      bf16x8 af = *(const bf16x8*)(arow + ks * 32);
#pragma unroll
      for (int ct = 0; ct < 8; ct++) {
        bf16x8 bfr = *(const bf16x8*)(w2t + (ct * 16 + l16) * HID + ks * 32 + quad * 8);
        acc[ct] = __builtin_amdgcn_mfma_f32_16x16x32_bf16(af, bfr, acc[ct], 0, 0, 0);
      }
    }
  }
  __syncthreads();  // all tt reads done; reuse smem as fp32 u tile
  float* uo = (float*)smem;
#pragma unroll
  for (int ct = 0; ct < 8; ct++) {
    int col = ct * 16 + l16;
    float bias = b2[col];
#pragma unroll
    for (int r = 0; r < 4; r++) {
      uo[(wave * 16 + quad * 4 + r) * US + col] = acc[ct][r] + bias;
    }
  }
  __syncthreads();

  // coalesced bf16 global store of u + per-block BN partial sums (fp32)
  for (int f = t; f < 64 * 32; f += 256) {
    int r = f >> 5, c4 = f & 31;
    if (r < nvalid) {
      f32x4 v = *(const f32x4*)(uo + r * US + c4 * 4);
      bf16x4 o = {(__bf16)v[0], (__bf16)v[1], (__bf16)v[2], (__bf16)v[3]};
      *(bf16x4*)(u + (size_t)(rowbase + r) * HID + c4 * 4) = o;
    }
  }
  if (t < HID) {
    float s = 0.f, sq = 0.f;
    for (int r = 0; r < nvalid; r++) {
      float v = uo[r * US + t];
      s += v;
      sq += v * v;
    }
    atomicAdd(&bnstats[t], s);
    atomicAdd(&bnstats[HID + t], sq);
  }
}

// ---------------- BN finalize: a = g*rsqrt(var+eps), b = beta - mean*a ------
__global__ __launch_bounds__(128) void bn_finalize_kernel(const float* __restrict__ bnstats,
                                                          const float* __restrict__ gamma,
                                                          const float* __restrict__ beta,
                                                          float* __restrict__ bnab) {
  int t = threadIdx.x;
  const float invN = 1.f / (float)N_NODES;
  float mean = bnstats[t] * invN;
  float var = bnstats[HID + t] * invN - mean * mean;
  float a = gamma[t] * rsqrtf(var + BN_EPS);
  bnab[t] = a;
  bnab[HID + t] = beta[t] - mean * a;
}

// ---------------- BN apply + mean-pool accumulate (layer 2, bf16 in) --------
__global__ __launch_bounds__(128) void bn_apply_pool_kernel(const __bf16* __restrict__ u,
                                                            const float* __restrict__ bnab,
                                                            const int* __restrict__ batch,
                                                            float* __restrict__ pool) {
  int c = threadIdx.x;  // feature column
  int r0 = blockIdx.x * 64;
  if (r0 >= N_NODES) return;
  int rend = min(r0 + 64, N_NODES);
  float a = bnab[c], b = bnab[HID + c];
  float accv = 0.f;
  int curg = -1;
  for (int r = r0; r < rend; r++) {
    int g = batch[r];
    if (g != curg) {
      if (curg >= 0) atomicAdd(&pool[curg * HID + c], accv);
      curg = g;
      accv = 0.f;
    }
    float v = (float)u[(size_t)r * HID + c];
    v = v * a + b;
    accv += (v > 0.f ? v : 0.f);
  }
  if (curg >= 0) atomicAdd(&pool[curg * HID + c], accv);
}

// ---------------- per-graph node counts (batch is sorted) -------------------
__global__ __launch_bounds__(256) void count_kernel(const int* __restrict__ batch,
                                                    int* __restrict__ counts) {
  int t = blockIdx.x * 256 + threadIdx.x;
  int r0 = t * 64;
  if (r0 >= N_NODES) return;
  int rend = min(r0 + 64, N_NODES);
  int curg = batch[r0], cnt = 0;
  for (int r = r0; r < rend; r++) {
    int g = batch[r];
    if (g != curg) {
      atomicAdd(&counts[curg], cnt);
      curg = g;
      cnt = 1;
    } else {
      cnt++;
    }
  }
  atomicAdd(&counts[curg], cnt);
}

// ---------------- hg = pool/cnt; out = hg @ proj_w + proj_b -----------------
__global__ __launch_bounds__(128) void pool_proj_kernel(const float* __restrict__ pool,
                                                        const int* __restrict__ counts,
                                                        const float* __restrict__ pw,
                                                        const float* __restrict__ pb,
                                                        float* __restrict__ out) {
  int g = blockIdx.x;
  int c = threadIdx.x;
  __shared__ float hg[HID];
  float cnt = (float)max(counts[g], 1);
  hg[c] = pool[g * HID + c] / cnt;
  __syncthreads();
  float acc = pb[c];
#pragma unroll 8
  for (int k = 0; k < HID; k++) acc += hg[k] * pw[k * HID + c];
  out[g * HID + c] = acc;
}

// ============================================================================
extern "C" void kernel_launch(void* const* d_in, const int* in_sizes, int n_in,
                              void* d_out, int out_size, void* d_ws, size_t ws_size,
                              hipStream_t stream) {
  (void)in_sizes; (void)n_in; (void)out_size; (void)ws_size;
  const float* x = (const float*)d_in[0];
  const int* ei = (const int*)d_in[1];
  const int* batch = (const int*)d_in[2];
  const float* w1[3] = {(const float*)d_in[3], (const float*)d_in[9], (const float*)d_in[15]};
  const float* b1[3] = {(const float*)d_in[4], (const float*)d_in[10], (const float*)d_in[16]};
  const float* w2[3] = {(const float*)d_in[5], (const float*)d_in[11], (const float*)d_in[17]};
  const float* b2[3] = {(const float*)d_in[6], (const float*)d_in[12], (const float*)d_in[18]};
  const float* gm[3] = {(const float*)d_in[7], (const float*)d_in[13], (const float*)d_in[19]};
  const float* bt[3] = {(const float*)d_in[8], (const float*)d_in[14], (const float*)d_in[20]};
  const float* pw = (const float*)d_in[21];
  const float* pb = (const float*)d_in[22];
  float* out = (float*)d_out;

  // workspace carve (ping-pong bf16 node buffers: no in-place read/write race)
  char* ws = (char*)d_ws;
  __bf16* hB0 = (__bf16*)ws;         ws += (size_t)N_NODES * HID * 2;   // 25.6 MB
  __bf16* hB1 = (__bf16*)ws;         ws += (size_t)N_NODES * HID * 2;   // 25.6 MB
  int* srcs = (int*)ws;              ws += (size_t)N_EDGES * 4;         // 6.4 MB
  int* ecounts = (int*)ws;           ws += (size_t)N_NODES * 4;
  int* starts = (int*)ws;            ws += (size_t)(N_NODES + 1) * 4;
  int* cursor = (int*)ws;            ws += (size_t)N_NODES * 4;
  __bf16* w1t0 = (__bf16*)ws;        ws += 128 * 64 * 2;
  __bf16* w2t0 = (__bf16*)ws;        ws += 128 * 128 * 2;
  __bf16* w1t1 = (__bf16*)ws;        ws += 128 * 128 * 2;
  __bf16* w2t1 = (__bf16*)ws;        ws += 128 * 128 * 2;
  __bf16* w1t2 = (__bf16*)ws;        ws += 128 * 128 * 2;
  __bf16* w2t2 = (__bf16*)ws;        ws += 128 * 128 * 2;
  float* bnstats = (float*)ws;       ws += 256 * 4;
  float* bnab = (float*)ws;          ws += 256 * 4;
  float* pool = (float*)ws;          ws += N_GRAPHS * HID * 4;          // contiguous with counts
  int* counts = (int*)ws;            ws += N_GRAPHS * 4;

  const int eblocks = (N_EDGES + 255) / 256;  // 6250
  const int mlp_blocks = (N_NODES + 63) / 64; // 1563

  // weight prep (bf16 transposed)
  prep_w_kernel<<<(128 * 64 + 255) / 256, 256, 0, stream>>>(w1[0], w1t0, 64);
  prep_w_kernel<<<(128 * 128 + 255) / 256, 256, 0, stream>>>(w2[0], w2t0, 128);
  prep_w_kernel<<<(128 * 128 + 255) / 256, 256, 0, stream>>>(w1[1], w1t1, 128);
  prep_w_kernel<<<(128 * 128 + 255) / 256, 256, 0, stream>>>(w2[1], w2t1, 128);
  prep_w_kernel<<<(128 * 128 + 255) / 256, 256, 0, stream>>>(w1[2], w1t2, 128);
  prep_w_kernel<<<(128 * 128 + 255) / 256, 256, 0, stream>>>(w2[2], w2t2, 128);

  // CSR build: histogram -> scan -> reorder
  hipMemsetAsync(ecounts, 0, (size_t)N_NODES * 4, stream);
  hist_kernel<<<eblocks, 256, 0, stream>>>(ei, ecounts);
  scan_kernel<<<1, 1024, 0, stream>>>(ecounts, starts, cursor);
  reorder_kernel<<<eblocks, 256, 0, stream>>>(ei, cursor, srcs);

  // zero pool + counts (contiguous), count nodes/graph
  hipMemsetAsync(pool, 0, (size_t)N_GRAPHS * HID * 4 + N_GRAPHS * 4, stream);
  count_kernel<<<((N_NODES + 63) / 64 + 255) / 256, 256, 0, stream>>>(batch, counts);

  // layer 0: x (fp32) -> hB0
  hipMemsetAsync(bnstats, 0, 256 * 4, stream);
  fused_mlp_kernel<64, false><<<mlp_blocks, 256, 0, stream>>>(
      x, starts, srcs, nullptr, w1t0, b1[0], w2t0, b2[0], hB0, bnstats);
  bn_finalize_kernel<<<1, 128, 0, stream>>>(bnstats, gm[0], bt[0], bnab);

  // layer 1: hB0 -> hB1
  hipMemsetAsync(bnstats, 0, 256 * 4, stream);
  fused_mlp_kernel<128, true><<<mlp_blocks, 256, 0, stream>>>(
      hB0, starts, srcs, bnab, w1t1, b1[1], w2t1, b2[1], hB1, bnstats);
  bn_finalize_kernel<<<1, 128, 0, stream>>>(bnstats, gm[1], bt[1], bnab);

  // layer 2: hB1 -> hB0
  hipMemsetAsync(bnstats, 0, 256 * 4, stream);
  fused_mlp_kernel<128, true><<<mlp_blocks, 256, 0, stream>>>(
      hB1, starts, srcs, bnab, w1t2, b1[2], w2t2, b2[2], hB0, bnstats);
  bn_finalize_kernel<<<1, 128, 0, stream>>>(bnstats, gm[2], bt[2], bnab);

  bn_apply_pool_kernel<<<mlp_blocks, 128, 0, stream>>>(hB0, bnab, batch, pool);

  pool_proj_kernel<<<N_GRAPHS, 128, 0, stream>>>(pool, counts, pw, pb, out);
}

// Round 4
// 1141.696 us; speedup vs baseline: 6.2614x; 1.0689x over previous
//
#include <hip/hip_runtime.h>

#define N_NODES 100000
#define N_EDGES 1600000
#define N_GRAPHS 256
#define HID 128
#define BN_EPS 1e-5f

typedef __bf16 bf16x8 __attribute__((ext_vector_type(8)));
typedef __bf16 bf16x4 __attribute__((ext_vector_type(4)));
typedef __bf16 bf16x2 __attribute__((ext_vector_type(2)));
typedef float f32x4 __attribute__((ext_vector_type(4)));

// ---------------- weight prep: W (K x 128 row-major) -> Wt bf16 (128 x K) ----
__global__ __launch_bounds__(256) void prep_w_kernel(const float* __restrict__ w,
                                                     __bf16* __restrict__ wt, int K) {
  int idx = blockIdx.x * 256 + threadIdx.x;
  if (idx >= 128 * K) return;
  int n = idx / K, k = idx - n * K;
  wt[idx] = (__bf16)w[k * 128 + n];
}

// ---------------- CSR build: histogram of dst ------------------------------
__global__ __launch_bounds__(256) void hist_kernel(const int* __restrict__ ei,
                                                   int* __restrict__ counts) {
  int e = blockIdx.x * 256 + threadIdx.x;
  if (e < N_EDGES) atomicAdd(&counts[ei[N_EDGES + e]], 1);
}

// ---------------- CSR build: single-block exclusive scan --------------------
__global__ __launch_bounds__(1024) void scan_kernel(const int* __restrict__ counts,
                                                    int* __restrict__ starts,
                                                    int* __restrict__ cursor) {
  __shared__ int ps[1024];
  int t = threadIdx.x;
  const int CH = (N_NODES + 1023) / 1024;  // 98
  int lo = t * CH, hi = min(lo + CH, N_NODES);
  int s = 0;
  for (int i = lo; i < hi; i++) s += counts[i];
  ps[t] = s;
  __syncthreads();
  for (int off = 1; off < 1024; off <<= 1) {
    int v = ps[t];
    int u = (t >= off) ? ps[t - off] : 0;
    __syncthreads();
    ps[t] = v + u;
    __syncthreads();
  }
  int base = (t == 0) ? 0 : ps[t - 1];
  for (int i = lo; i < hi; i++) {
    starts[i] = base;
    cursor[i] = base;
    base += counts[i];
  }
  if (t == 1023) starts[N_NODES] = ps[1023];
}

// ---------------- CSR build: reorder src by dst bucket ----------------------
__global__ __launch_bounds__(256) void reorder_kernel(const int* __restrict__ ei,
                                                      int* __restrict__ cursor,
                                                      int* __restrict__ srcs) {
  int e = blockIdx.x * 256 + threadIdx.x;
  if (e >= N_EDGES) return;
  int dst = ei[N_EDGES + e];
  int pos = atomicAdd(&cursor[dst], 1);
  srcs[pos] = ei[e];
}

// ---------------- fused gather + MLP ----------------------------------------
// CIN==64: in_ is fp32 x (no BN).  CIN==128: in_ is bf16 pre-BN u of prev layer.
// h = DOBN ? relu(a*in+b) : in ; z_row = h_row + sum_{CSR[row]} h_src
// u = relu(z @ W1 + b1) @ W2 + b2  (stored bf16); BN partial sums from fp32.
template <int CIN, bool DOBN>
__global__ __launch_bounds__(256) void fused_mlp_kernel(
    const void* __restrict__ in_, const int* __restrict__ starts,
    const int* __restrict__ srcs, const float* __restrict__ bnab,
    const __bf16* __restrict__ w1t, const float* __restrict__ b1,
    const __bf16* __restrict__ w2t, const float* __restrict__ b2,
    __bf16* __restrict__ u, float* __restrict__ bnstats) {
  constexpr int ZS = CIN + 8;   // bf16 elems/row (+pad)
  constexpr int TS = HID + 8;   // bf16 elems/row (+pad)
  constexpr int US = 132;       // fp32 elems/row (+pad)
  constexpr int ZB = 64 * ZS * 2;
  constexpr int TB = 64 * TS * 2;
  constexpr int UB = 64 * US * 4;
  constexpr int SB = (ZB + TB) > UB ? (ZB + TB) : UB;
  __shared__ __align__(16) char smem[SB];
  __bf16* zt = (__bf16*)smem;
  __bf16* tt = (__bf16*)(smem + ZB);

  const int t = threadIdx.x;
  const int wave = t >> 6;
  const int lane = t & 63;
  const int l16 = lane & 15;
  const int quad = lane >> 4;
  const int rowbase = blockIdx.x * 64;
  const int nvalid = min(64, N_NODES - rowbase);

  // Phase A: gather-aggregate (+BN/relu of input), z -> LDS (bf16)
  // Key: fetch the whole row's edge indices in ONE coalesced load (lane e0+lane),
  // then v_readlane-broadcast each index -> back-to-back independent gathers.
  if constexpr (CIN == 64) {
    const float* in = (const float*)in_;
    for (int r = wave; r < 64; r += 4) {
      int gr = rowbase + r;
      float acc = 0.f;
      if (gr < N_NODES) {
        int e0 = starts[gr], e1 = starts[gr + 1];
        int deg = e1 - e0;
        int idxv = srcs[min(e0 + lane, N_EDGES - 1)];
        acc = in[(size_t)gr * 64 + lane];
        float s0 = 0.f, s1 = 0.f, s2 = 0.f, s3 = 0.f;
        int dcap = min(deg, 64);
        int j = 0;
        for (; j + 3 < dcap; j += 4) {
          int i0 = __builtin_amdgcn_readlane(idxv, j);
          int i1 = __builtin_amdgcn_readlane(idxv, j + 1);
          int i2 = __builtin_amdgcn_readlane(idxv, j + 2);
          int i3 = __builtin_amdgcn_readlane(idxv, j + 3);
          float v0 = in[(size_t)i0 * 64 + lane];
          float v1 = in[(size_t)i1 * 64 + lane];
          float v2 = in[(size_t)i2 * 64 + lane];
          float v3 = in[(size_t)i3 * 64 + lane];
          s0 += v0; s1 += v1; s2 += v2; s3 += v3;
        }
        for (; j < dcap; j++) {
          int i0 = __builtin_amdgcn_readlane(idxv, j);
          s0 += in[(size_t)i0 * 64 + lane];
        }
        for (int e = e0 + 64; e < e1; e++) s0 += in[(size_t)srcs[e] * 64 + lane];
        acc += (s0 + s1) + (s2 + s3);
      }
      zt[r * ZS + lane] = (__bf16)acc;
    }
  } else {
    const __bf16* in = (const __bf16*)in_;
    float2 av = {1.f, 1.f}, bv = {0.f, 0.f};
    if (DOBN) {
      av = ((const float2*)bnab)[lane];
      bv = ((const float2*)(bnab + HID))[lane];
    }
    for (int r = wave; r < 64; r += 4) {
      int gr = rowbase + r;
      float ax = 0.f, ay = 0.f;
      if (gr < N_NODES) {
        int e0 = starts[gr], e1 = starts[gr + 1];
        int deg = e1 - e0;
        int idxv = srcs[min(e0 + lane, N_EDGES - 1)];
        bf16x2 v = *(const bf16x2*)(in + (size_t)gr * 128 + lane * 2);
        if (DOBN) {
          ax = fmaxf(fmaf(av.x, (float)v[0], bv.x), 0.f);
          ay = fmaxf(fmaf(av.y, (float)v[1], bv.y), 0.f);
        } else {
          ax = (float)v[0]; ay = (float)v[1];
        }
        float2 s0 = {0.f, 0.f}, s1 = {0.f, 0.f}, s2 = {0.f, 0.f}, s3 = {0.f, 0.f};
        int dcap = min(deg, 64);
        int j = 0;
        for (; j + 3 < dcap; j += 4) {
          int i0 = __builtin_amdgcn_readlane(idxv, j);
          int i1 = __builtin_amdgcn_readlane(idxv, j + 1);
          int i2 = __builtin_amdgcn_readlane(idxv, j + 2);
          int i3 = __builtin_amdgcn_readlane(idxv, j + 3);
          bf16x2 v0 = *(const bf16x2*)(in + (size_t)i0 * 128 + lane * 2);
          bf16x2 v1 = *(const bf16x2*)(in + (size_t)i1 * 128 + lane * 2);
          bf16x2 v2 = *(const bf16x2*)(in + (size_t)i2 * 128 + lane * 2);
          bf16x2 v3 = *(const bf16x2*)(in + (size_t)i3 * 128 + lane * 2);
          if (DOBN) {
            s0.x += fmaxf(fmaf(av.x, (float)v0[0], bv.x), 0.f);
            s0.y += fmaxf(fmaf(av.y, (float)v0[1], bv.y), 0.f);
            s1.x += fmaxf(fmaf(av.x, (float)v1[0], bv.x), 0.f);
            s1.y += fmaxf(fmaf(av.y, (float)v1[1], bv.y), 0.f);
            s2.x += fmaxf(fmaf(av.x, (float)v2[0], bv.x), 0.f);
            s2.y += fmaxf(fmaf(av.y, (float)v2[1], bv.y), 0.f);
            s3.x += fmaxf(fmaf(av.x, (float)v3[0], bv.x), 0.f);
            s3.y += fmaxf(fmaf(av.y, (float)v3[1], bv.y), 0.f);
          } else {
            s0.x += (float)v0[0]; s0.y += (float)v0[1];
            s1.x += (float)v1[0]; s1.y += (float)v1[1];
            s2.x += (float)v2[0]; s2.y += (float)v2[1];
            s3.x += (float)v3[0]; s3.y += (float)v3[1];
          }
        }
        for (; j < dcap; j++) {
          int i0 = __builtin_amdgcn_readlane(idxv, j);
          bf16x2 vv = *(const bf16x2*)(in + (size_t)i0 * 128 + lane * 2);
          if (DOBN) {
            s0.x += fmaxf(fmaf(av.x, (float)vv[0], bv.x), 0.f);
            s0.y += fmaxf(fmaf(av.y, (float)vv[1], bv.y), 0.f);
          } else {
            s0.x += (float)vv[0]; s0.y += (float)vv[1];
          }
        }
        for (int e = e0 + 64; e < e1; e++) {
          bf16x2 vv = *(const bf16x2*)(in + (size_t)srcs[e] * 128 + lane * 2);
          if (DOBN) {
            s0.x += fmaxf(fmaf(av.x, (float)vv[0], bv.x), 0.f);
            s0.y += fmaxf(fmaf(av.y, (float)vv[1], bv.y), 0.f);
          } else {
            s0.x += (float)vv[0]; s0.y += (float)vv[1];
          }
        }
        ax += (s0.x + s1.x) + (s2.x + s3.x);
        ay += (s0.y + s1.y) + (s2.y + s3.y);
      }
      bf16x2 z2 = {(__bf16)ax, (__bf16)ay};
      *(bf16x2*)(zt + r * ZS + lane * 2) = z2;
    }
  }
  __syncthreads();

  const f32x4 zero4 = {0.f, 0.f, 0.f, 0.f};
  f32x4 acc[8];

  // Phase B: t = relu(z @ W1 + b1) -> LDS (bf16)
  {
#pragma unroll
    for (int ct = 0; ct < 8; ct++) acc[ct] = zero4;
    const __bf16* arow = zt + (wave * 16 + l16) * ZS + quad * 8;
#pragma unroll
    for (int ks = 0; ks < CIN / 32; ks++) {
      bf16x8 af = *(const bf16x8*)(arow + ks * 32);
#pragma unroll
      for (int ct = 0; ct < 8; ct++) {
        bf16x8 bfr = *(const bf16x8*)(w1t + (ct * 16 + l16) * CIN + ks * 32 + quad * 8);
        acc[ct] = __builtin_amdgcn_mfma_f32_16x16x32_bf16(af, bfr, acc[ct], 0, 0, 0);
      }
    }
#pragma unroll
    for (int ct = 0; ct < 8; ct++) {
      int col = ct * 16 + l16;
      float bias = b1[col];
#pragma unroll
      for (int r = 0; r < 4; r++) {
        float v = acc[ct][r] + bias;
        tt[(wave * 16 + quad * 4 + r) * TS + col] = (__bf16)(v > 0.f ? v : 0.f);
      }
    }
  }
  __syncthreads();

  // Phase C: u = t @ W2 + b2
  {
#pragma unroll
    for (int ct = 0; ct < 8; ct++) acc[ct] = zero4;
    const __bf16* arow = tt + (wave * 16 + l16) * TS + quad * 8;
#pragma unroll
    for (int ks = 0; ks < HID / 32; ks++) {
      bf16x8 af = *(const bf16x8*)(arow + ks * 32);
#pragma unroll
      for (int ct = 0; ct < 8; ct++) {
        bf16x8 bfr = *(const bf16x8*)(w2t + (ct * 16 + l16) * HID + ks * 32 + quad * 8);
        acc[ct] = __builtin_amdgcn_mfma_f32_16x16x32_bf16(af, bfr, acc[ct], 0, 0, 0);
      }
    }
  }
  __syncthreads();  // all tt reads done; reuse smem as fp32 u tile
  float* uo = (float*)smem;
#pragma unroll
  for (int ct = 0; ct < 8; ct++) {
    int col = ct * 16 + l16;
    float bias = b2[col];
#pragma unroll
    for (int r = 0; r < 4; r++) {
      uo[(wave * 16 + quad * 4 + r) * US + col] = acc[ct][r] + bias;
    }
  }
  __syncthreads();

  // coalesced bf16 global store of u + per-block BN partial sums (fp32)
  for (int f = t; f < 64 * 32; f += 256) {
    int r = f >> 5, c4 = f & 31;
    if (r < nvalid) {
      f32x4 v = *(const f32x4*)(uo + r * US + c4 * 4);
      bf16x4 o = {(__bf16)v[0], (__bf16)v[1], (__bf16)v[2], (__bf16)v[3]};
      *(bf16x4*)(u + (size_t)(rowbase + r) * HID + c4 * 4) = o;
    }
  }
  if (t < HID) {
    float s = 0.f, sq = 0.f;
    for (int r = 0; r < nvalid; r++) {
      float v = uo[r * US + t];
      s += v;
      sq += v * v;
    }
    atomicAdd(&bnstats[t], s);
    atomicAdd(&bnstats[HID + t], sq);
  }
}

// ---------------- BN finalize: a = g*rsqrt(var+eps), b = beta - mean*a ------
__global__ __launch_bounds__(128) void bn_finalize_kernel(const float* __restrict__ bnstats,
                                                          const float* __restrict__ gamma,
                                                          const float* __restrict__ beta,
                                                          float* __restrict__ bnab) {
  int t = threadIdx.x;
  const float invN = 1.f / (float)N_NODES;
  float mean = bnstats[t] * invN;
  float var = bnstats[HID + t] * invN - mean * mean;
  float a = gamma[t] * rsqrtf(var + BN_EPS);
  bnab[t] = a;
  bnab[HID + t] = beta[t] - mean * a;
}

// ---------------- BN apply + mean-pool accumulate (layer 2, bf16 in) --------
__global__ __launch_bounds__(128) void bn_apply_pool_kernel(const __bf16* __restrict__ u,
                                                            const float* __restrict__ bnab,
                                                            const int* __restrict__ batch,
                                                            float* __restrict__ pool) {
  int c = threadIdx.x;  // feature column
  int r0 = blockIdx.x * 64;
  if (r0 >= N_NODES) return;
  int rend = min(r0 + 64, N_NODES);
  float a = bnab[c], b = bnab[HID + c];
  float accv = 0.f;
  int curg = -1;
  for (int r = r0; r < rend; r++) {
    int g = batch[r];
    if (g != curg) {
      if (curg >= 0) atomicAdd(&pool[curg * HID + c], accv);
      curg = g;
      accv = 0.f;
    }
    float v = (float)u[(size_t)r * HID + c];
    v = v * a + b;
    accv += (v > 0.f ? v : 0.f);
  }
  if (curg >= 0) atomicAdd(&pool[curg * HID + c], accv);
}

// ---------------- per-graph node counts (batch is sorted) -------------------
__global__ __launch_bounds__(256) void count_kernel(const int* __restrict__ batch,
                                                    int* __restrict__ counts) {
  int t = blockIdx.x * 256 + threadIdx.x;
  int r0 = t * 64;
  if (r0 >= N_NODES) return;
  int rend = min(r0 + 64, N_NODES);
  int curg = batch[r0], cnt = 0;
  for (int r = r0; r < rend; r++) {
    int g = batch[r];
    if (g != curg) {
      atomicAdd(&counts[curg], cnt);
      curg = g;
      cnt = 1;
    } else {
      cnt++;
    }
  }
  atomicAdd(&counts[curg], cnt);
}

// ---------------- hg = pool/cnt; out = hg @ proj_w + proj_b -----------------
__global__ __launch_bounds__(128) void pool_proj_kernel(const float* __restrict__ pool,
                                                        const int* __restrict__ counts,
                                                        const float* __restrict__ pw,
                                                        const float* __restrict__ pb,
                                                        float* __restrict__ out) {
  int g = blockIdx.x;
  int c = threadIdx.x;
  __shared__ float hg[HID];
  float cnt = (float)max(counts[g], 1);
  hg[c] = pool[g * HID + c] / cnt;
  __syncthreads();
  float acc = pb[c];
#pragma unroll 8
  for (int k = 0; k < HID; k++) acc += hg[k] * pw[k * HID + c];
  out[g * HID + c] = acc;
}

// ============================================================================
extern "C" void kernel_launch(void* const* d_in, const int* in_sizes, int n_in,
                              void* d_out, int out_size, void* d_ws, size_t ws_size,
                              hipStream_t stream) {
  (void)in_sizes; (void)n_in; (void)out_size; (void)ws_size;
  const float* x = (const float*)d_in[0];
  const int* ei = (const int*)d_in[1];
  const int* batch = (const int*)d_in[2];
  const float* w1[3] = {(const float*)d_in[3], (const float*)d_in[9], (const float*)d_in[15]};
  const float* b1[3] = {(const float*)d_in[4], (const float*)d_in[10], (const float*)d_in[16]};
  const float* w2[3] = {(const float*)d_in[5], (const float*)d_in[11], (const float*)d_in[17]};
  const float* b2[3] = {(const float*)d_in[6], (const float*)d_in[12], (const float*)d_in[18]};
  const float* gm[3] = {(const float*)d_in[7], (const float*)d_in[13], (const float*)d_in[19]};
  const float* bt[3] = {(const float*)d_in[8], (const float*)d_in[14], (const float*)d_in[20]};
  const float* pw = (const float*)d_in[21];
  const float* pb = (const float*)d_in[22];
  float* out = (float*)d_out;

  // workspace carve (ping-pong bf16 node buffers: no in-place read/write race)
  char* ws = (char*)d_ws;
  __bf16* hB0 = (__bf16*)ws;         ws += (size_t)N_NODES * HID * 2;   // 25.6 MB
  __bf16* hB1 = (__bf16*)ws;         ws += (size_t)N_NODES * HID * 2;   // 25.6 MB
  int* srcs = (int*)ws;              ws += (size_t)N_EDGES * 4;         // 6.4 MB
  int* ecounts = (int*)ws;           ws += (size_t)N_NODES * 4;
  int* starts = (int*)ws;            ws += (size_t)(N_NODES + 1) * 4;
  int* cursor = (int*)ws;            ws += (size_t)N_NODES * 4;
  __bf16* w1t0 = (__bf16*)ws;        ws += 128 * 64 * 2;
  __bf16* w2t0 = (__bf16*)ws;        ws += 128 * 128 * 2;
  __bf16* w1t1 = (__bf16*)ws;        ws += 128 * 128 * 2;
  __bf16* w2t1 = (__bf16*)ws;        ws += 128 * 128 * 2;
  __bf16* w1t2 = (__bf16*)ws;        ws += 128 * 128 * 2;
  __bf16* w2t2 = (__bf16*)ws;        ws += 128 * 128 * 2;
  float* bnstats = (float*)ws;       ws += 256 * 4;
  float* bnab = (float*)ws;          ws += 256 * 4;
  float* pool = (float*)ws;          ws += N_GRAPHS * HID * 4;          // contiguous with counts
  int* counts = (int*)ws;            ws += N_GRAPHS * 4;

  const int eblocks = (N_EDGES + 255) / 256;  // 6250
  const int mlp_blocks = (N_NODES + 63) / 64; // 1563

  // weight prep (bf16 transposed)
  prep_w_kernel<<<(128 * 64 + 255) / 256, 256, 0, stream>>>(w1[0], w1t0, 64);
  prep_w_kernel<<<(128 * 128 + 255) / 256, 256, 0, stream>>>(w2[0], w2t0, 128);
  prep_w_kernel<<<(128 * 128 + 255) / 256, 256, 0, stream>>>(w1[1], w1t1, 128);
  prep_w_kernel<<<(128 * 128 + 255) / 256, 256, 0, stream>>>(w2[1], w2t1, 128);
  prep_w_kernel<<<(128 * 128 + 255) / 256, 256, 0, stream>>>(w1[2], w1t2, 128);
  prep_w_kernel<<<(128 * 128 + 255) / 256, 256, 0, stream>>>(w2[2], w2t2, 128);

  // CSR build: histogram -> scan -> reorder
  hipMemsetAsync(ecounts, 0, (size_t)N_NODES * 4, stream);
  hist_kernel<<<eblocks, 256, 0, stream>>>(ei, ecounts);
  scan_kernel<<<1, 1024, 0, stream>>>(ecounts, starts, cursor);
  reorder_kernel<<<eblocks, 256, 0, stream>>>(ei, cursor, srcs);

  // zero pool + counts (contiguous), count nodes/graph
  hipMemsetAsync(pool, 0, (size_t)N_GRAPHS * HID * 4 + N_GRAPHS * 4, stream);
  count_kernel<<<((N_NODES + 63) / 64 + 255) / 256, 256, 0, stream>>>(batch, counts);

  // layer 0: x (fp32) -> hB0
  hipMemsetAsync(bnstats, 0, 256 * 4, stream);
  fused_mlp_kernel<64, false><<<mlp_blocks, 256, 0, stream>>>(
      x, starts, srcs, nullptr, w1t0, b1[0], w2t0, b2[0], hB0, bnstats);
  bn_finalize_kernel<<<1, 128, 0, stream>>>(bnstats, gm[0], bt[0], bnab);

  // layer 1: hB0 -> hB1
  hipMemsetAsync(bnstats, 0, 256 * 4, stream);
  fused_mlp_kernel<128, true><<<mlp_blocks, 256, 0, stream>>>(
      hB0, starts, srcs, bnab, w1t1, b1[1], w2t1, b2[1], hB1, bnstats);
  bn_finalize_kernel<<<1, 128, 0, stream>>>(bnstats, gm[1], bt[1], bnab);

  // layer 2: hB1 -> hB0
  hipMemsetAsync(bnstats, 0, 256 * 4, stream);
  fused_mlp_kernel<128, true><<<mlp_blocks, 256, 0, stream>>>(
      hB1, starts, srcs, bnab, w1t2, b1[2], w2t2, b2[2], hB0, bnstats);
  bn_finalize_kernel<<<1, 128, 0, stream>>>(bnstats, gm[2], bt[2], bnab);

  bn_apply_pool_kernel<<<mlp_blocks, 128, 0, stream>>>(hB0, bnab, batch, pool);

  pool_proj_kernel<<<N_GRAPHS, 128, 0, stream>>>(pool, counts, pw, pb, out);
}

// Round 5
// 877.726 us; speedup vs baseline: 8.1444x; 1.3007x over previous
//
#include <hip/hip_runtime.h>

#define N_NODES 100000
#define N_EDGES 1600000
#define N_GRAPHS 256
#define HID 128
#define BN_EPS 1e-5f

typedef __bf16 bf16x8 __attribute__((ext_vector_type(8)));
typedef __bf16 bf16x4 __attribute__((ext_vector_type(4)));
typedef __bf16 bf16x2 __attribute__((ext_vector_type(2)));
typedef float f32x4 __attribute__((ext_vector_type(4)));

#define SCAN_NB ((N_NODES + 255) / 256)  // 391

// ---------------- weight prep: all 6 weights -> one bf16 transposed buffer --
// segs: w1_0 (K=64, off 0), then w2_0,w1_1,w2_1,w1_2,w2_2 (K=128)
__global__ __launch_bounds__(256) void prep_all_kernel(
    const float* __restrict__ wa, const float* __restrict__ wb,
    const float* __restrict__ wc, const float* __restrict__ wd,
    const float* __restrict__ we, const float* __restrict__ wf,
    __bf16* __restrict__ wt) {
  int idx = blockIdx.x * 256 + threadIdx.x;
  if (idx >= 90112) return;
  const float* w;
  int K, local;
  if (idx < 8192) { w = wa; K = 64; local = idx; }
  else {
    int s = (idx - 8192) / 16384;
    local = (idx - 8192) - s * 16384;
    K = 128;
    w = (s == 0) ? wb : (s == 1) ? wc : (s == 2) ? wd : (s == 3) ? we : wf;
  }
  int n = local / K, k = local - n * K;
  wt[idx] = (__bf16)w[k * 128 + n];
}

// ---------------- CSR build: histogram of dst ------------------------------
__global__ __launch_bounds__(256) void hist_kernel(const int* __restrict__ ei,
                                                   int* __restrict__ counts) {
  int e = blockIdx.x * 256 + threadIdx.x;
  if (e < N_EDGES) atomicAdd(&counts[ei[N_EDGES + e]], 1);
}

// ---------------- scan step 1: per-block local exclusive scan ---------------
__global__ __launch_bounds__(256) void local_scan_kernel(const int* __restrict__ counts,
                                                         int* __restrict__ starts,
                                                         int* __restrict__ btot) {
  __shared__ int ps[256];
  int t = threadIdx.x;
  int i = blockIdx.x * 256 + t;
  int c = (i < N_NODES) ? counts[i] : 0;
  ps[t] = c;
  __syncthreads();
  for (int off = 1; off < 256; off <<= 1) {
    int v = ps[t];
    int u = (t >= off) ? ps[t - off] : 0;
    __syncthreads();
    ps[t] = v + u;
    __syncthreads();
  }
  if (i < N_NODES) starts[i] = ps[t] - c;  // local exclusive
  if (t == 255) btot[blockIdx.x] = ps[255];
}

// ---------------- scan step 2: scan the 391 block totals --------------------
__global__ __launch_bounds__(512) void scan_totals_kernel(const int* __restrict__ btot,
                                                          int* __restrict__ boff,
                                                          int* __restrict__ starts) {
  __shared__ int ps[512];
  int t = threadIdx.x;
  int v = (t < SCAN_NB) ? btot[t] : 0;
  ps[t] = v;
  __syncthreads();
  for (int off = 1; off < 512; off <<= 1) {
    int a = ps[t];
    int u = (t >= off) ? ps[t - off] : 0;
    __syncthreads();
    ps[t] = a + u;
    __syncthreads();
  }
  if (t < SCAN_NB) boff[t] = ps[t] - v;  // exclusive
  if (t == 511) starts[N_NODES] = ps[511];
}

// ---------------- scan step 3: add offsets, write starts + cursor -----------
__global__ __launch_bounds__(256) void add_off_kernel(int* __restrict__ starts,
                                                      const int* __restrict__ boff,
                                                      int* __restrict__ cursor) {
  int i = blockIdx.x * 256 + threadIdx.x;
  if (i >= N_NODES) return;
  int v = starts[i] + boff[blockIdx.x];
  starts[i] = v;
  cursor[i] = v;
}

// ---------------- CSR build: reorder src by dst bucket ----------------------
__global__ __launch_bounds__(256) void reorder_kernel(const int* __restrict__ ei,
                                                      int* __restrict__ cursor,
                                                      int* __restrict__ srcs) {
  int e = blockIdx.x * 256 + threadIdx.x;
  if (e >= N_EDGES) return;
  int dst = ei[N_EDGES + e];
  int pos = atomicAdd(&cursor[dst], 1);
  srcs[pos] = ei[e];
}

// ---------------- fused gather + MLP ----------------------------------------
// CIN==64: in_ is fp32 x (no BN).  CIN==128: in_ is bf16 pre-BN u of prev layer.
// h = DOBN ? relu(a*in+b) : in ; z_row = h_row + sum_{CSR[row]} h_src
// u = relu(z @ W1 + b1) @ W2 + b2  (stored bf16); BN partial sums from fp32.
template <int CIN, bool DOBN>
__global__ __launch_bounds__(256) void fused_mlp_kernel(
    const void* __restrict__ in_, const int* __restrict__ starts,
    const int* __restrict__ srcs, const float* __restrict__ bnab,
    const __bf16* __restrict__ w1t, const float* __restrict__ b1,
    const __bf16* __restrict__ w2t, const float* __restrict__ b2,
    __bf16* __restrict__ u, float* __restrict__ bnstats) {
  constexpr int ZS = CIN + 8;   // bf16 elems/row (+pad)
  constexpr int TS = HID + 8;   // bf16 elems/row (+pad)
  constexpr int US = 132;       // fp32 elems/row (+pad)
  constexpr int ZB = 64 * ZS * 2;
  constexpr int TB = 64 * TS * 2;
  constexpr int UB = 64 * US * 4;
  constexpr int SB = (ZB + TB) > UB ? (ZB + TB) : UB;
  __shared__ __align__(16) char smem[SB];
  __bf16* zt = (__bf16*)smem;
  __bf16* tt = (__bf16*)(smem + ZB);

  const int t = threadIdx.x;
  const int wave = t >> 6;
  const int lane = t & 63;
  const int l16 = lane & 15;
  const int quad = lane >> 4;
  const int rowbase = blockIdx.x * 64;
  const int nvalid = min(64, N_NODES - rowbase);

  // Phase A: gather-aggregate (+BN/relu of input), z -> LDS (bf16)
  // Fetch whole row's edge indices in ONE coalesced load, then readlane-
  // broadcast -> back-to-back independent gathers (4 accumulators).
  if constexpr (CIN == 64) {
    const float* in = (const float*)in_;
    for (int r = wave; r < 64; r += 4) {
      int gr = rowbase + r;
      float acc = 0.f;
      if (gr < N_NODES) {
        int e0 = starts[gr], e1 = starts[gr + 1];
        int deg = e1 - e0;
        int idxv = srcs[min(e0 + lane, N_EDGES - 1)];
        acc = in[(size_t)gr * 64 + lane];
        float s0 = 0.f, s1 = 0.f, s2 = 0.f, s3 = 0.f;
        int dcap = min(deg, 64);
        int j = 0;
        for (; j + 3 < dcap; j += 4) {
          int i0 = __builtin_amdgcn_readlane(idxv, j);
          int i1 = __builtin_amdgcn_readlane(idxv, j + 1);
          int i2 = __builtin_amdgcn_readlane(idxv, j + 2);
          int i3 = __builtin_amdgcn_readlane(idxv, j + 3);
          float v0 = in[(size_t)i0 * 64 + lane];
          float v1 = in[(size_t)i1 * 64 + lane];
          float v2 = in[(size_t)i2 * 64 + lane];
          float v3 = in[(size_t)i3 * 64 + lane];
          s0 += v0; s1 += v1; s2 += v2; s3 += v3;
        }
        for (; j < dcap; j++) {
          int i0 = __builtin_amdgcn_readlane(idxv, j);
          s0 += in[(size_t)i0 * 64 + lane];
        }
        for (int e = e0 + 64; e < e1; e++) s0 += in[(size_t)srcs[e] * 64 + lane];
        acc += (s0 + s1) + (s2 + s3);
      }
      zt[r * ZS + lane] = (__bf16)acc;
    }
  } else {
    const __bf16* in = (const __bf16*)in_;
    float2 av = {1.f, 1.f}, bv = {0.f, 0.f};
    if (DOBN) {
      av = ((const float2*)bnab)[lane];
      bv = ((const float2*)(bnab + HID))[lane];
    }
    for (int r = wave; r < 64; r += 4) {
      int gr = rowbase + r;
      float ax = 0.f, ay = 0.f;
      if (gr < N_NODES) {
        int e0 = starts[gr], e1 = starts[gr + 1];
        int deg = e1 - e0;
        int idxv = srcs[min(e0 + lane, N_EDGES - 1)];
        bf16x2 v = *(const bf16x2*)(in + (size_t)gr * 128 + lane * 2);
        if (DOBN) {
          ax = fmaxf(fmaf(av.x, (float)v[0], bv.x), 0.f);
          ay = fmaxf(fmaf(av.y, (float)v[1], bv.y), 0.f);
        } else {
          ax = (float)v[0]; ay = (float)v[1];
        }
        float2 s0 = {0.f, 0.f}, s1 = {0.f, 0.f}, s2 = {0.f, 0.f}, s3 = {0.f, 0.f};
        int dcap = min(deg, 64);
        int j = 0;
        for (; j + 3 < dcap; j += 4) {
          int i0 = __builtin_amdgcn_readlane(idxv, j);
          int i1 = __builtin_amdgcn_readlane(idxv, j + 1);
          int i2 = __builtin_amdgcn_readlane(idxv, j + 2);
          int i3 = __builtin_amdgcn_readlane(idxv, j + 3);
          bf16x2 v0 = *(const bf16x2*)(in + (size_t)i0 * 128 + lane * 2);
          bf16x2 v1 = *(const bf16x2*)(in + (size_t)i1 * 128 + lane * 2);
          bf16x2 v2 = *(const bf16x2*)(in + (size_t)i2 * 128 + lane * 2);
          bf16x2 v3 = *(const bf16x2*)(in + (size_t)i3 * 128 + lane * 2);
          if (DOBN) {
            s0.x += fmaxf(fmaf(av.x, (float)v0[0], bv.x), 0.f);
            s0.y += fmaxf(fmaf(av.y, (float)v0[1], bv.y), 0.f);
            s1.x += fmaxf(fmaf(av.x, (float)v1[0], bv.x), 0.f);
            s1.y += fmaxf(fmaf(av.y, (float)v1[1], bv.y), 0.f);
            s2.x += fmaxf(fmaf(av.x, (float)v2[0], bv.x), 0.f);
            s2.y += fmaxf(fmaf(av.y, (float)v2[1], bv.y), 0.f);
            s3.x += fmaxf(fmaf(av.x, (float)v3[0], bv.x), 0.f);
            s3.y += fmaxf(fmaf(av.y, (float)v3[1], bv.y), 0.f);
          } else {
            s0.x += (float)v0[0]; s0.y += (float)v0[1];
            s1.x += (float)v1[0]; s1.y += (float)v1[1];
            s2.x += (float)v2[0]; s2.y += (float)v2[1];
            s3.x += (float)v3[0]; s3.y += (float)v3[1];
          }
        }
        for (; j < dcap; j++) {
          int i0 = __builtin_amdgcn_readlane(idxv, j);
          bf16x2 vv = *(const bf16x2*)(in + (size_t)i0 * 128 + lane * 2);
          if (DOBN) {
            s0.x += fmaxf(fmaf(av.x, (float)vv[0], bv.x), 0.f);
            s0.y += fmaxf(fmaf(av.y, (float)vv[1], bv.y), 0.f);
          } else {
            s0.x += (float)vv[0]; s0.y += (float)vv[1];
          }
        }
        for (int e = e0 + 64; e < e1; e++) {
          bf16x2 vv = *(const bf16x2*)(in + (size_t)srcs[e] * 128 + lane * 2);
          if (DOBN) {
            s0.x += fmaxf(fmaf(av.x, (float)vv[0], bv.x), 0.f);
            s0.y += fmaxf(fmaf(av.y, (float)vv[1], bv.y), 0.f);
          } else {
            s0.x += (float)vv[0]; s0.y += (float)vv[1];
          }
        }
        ax += (s0.x + s1.x) + (s2.x + s3.x);
        ay += (s0.y + s1.y) + (s2.y + s3.y);
      }
      bf16x2 z2 = {(__bf16)ax, (__bf16)ay};
      *(bf16x2*)(zt + r * ZS + lane * 2) = z2;
    }
  }
  __syncthreads();

  const f32x4 zero4 = {0.f, 0.f, 0.f, 0.f};
  f32x4 acc[8];

  // Phase B: t = relu(z @ W1 + b1) -> LDS (bf16)
  {
#pragma unroll
    for (int ct = 0; ct < 8; ct++) acc[ct] = zero4;
    const __bf16* arow = zt + (wave * 16 + l16) * ZS + quad * 8;
#pragma unroll
    for (int ks = 0; ks < CIN / 32; ks++) {
      bf16x8 af = *(const bf16x8*)(arow + ks * 32);
#pragma unroll
      for (int ct = 0; ct < 8; ct++) {
        bf16x8 bfr = *(const bf16x8*)(w1t + (ct * 16 + l16) * CIN + ks * 32 + quad * 8);
        acc[ct] = __builtin_amdgcn_mfma_f32_16x16x32_bf16(af, bfr, acc[ct], 0, 0, 0);
      }
    }
#pragma unroll
    for (int ct = 0; ct < 8; ct++) {
      int col = ct * 16 + l16;
      float bias = b1[col];
#pragma unroll
      for (int r = 0; r < 4; r++) {
        float v = acc[ct][r] + bias;
        tt[(wave * 16 + quad * 4 + r) * TS + col] = (__bf16)(v > 0.f ? v : 0.f);
      }
    }
  }
  __syncthreads();

  // Phase C: u = t @ W2 + b2
  {
#pragma unroll
    for (int ct = 0; ct < 8; ct++) acc[ct] = zero4;
    const __bf16* arow = tt + (wave * 16 + l16) * TS + quad * 8;
#pragma unroll
    for (int ks = 0; ks < HID / 32; ks++) {
      bf16x8 af = *(const bf16x8*)(arow + ks * 32);
#pragma unroll
      for (int ct = 0; ct < 8; ct++) {
        bf16x8 bfr = *(const bf16x8*)(w2t + (ct * 16 + l16) * HID + ks * 32 + quad * 8);
        acc[ct] = __builtin_amdgcn_mfma_f32_16x16x32_bf16(af, bfr, acc[ct], 0, 0, 0);
      }
    }
  }
  __syncthreads();  // all tt reads done; reuse smem as fp32 u tile
  float* uo = (float*)smem;
#pragma unroll
  for (int ct = 0; ct < 8; ct++) {
    int col = ct * 16 + l16;
    float bias = b2[col];
#pragma unroll
    for (int r = 0; r < 4; r++) {
      uo[(wave * 16 + quad * 4 + r) * US + col] = acc[ct][r] + bias;
    }
  }
  __syncthreads();

  // coalesced bf16 global store of u + per-block BN partial sums (fp32)
  for (int f = t; f < 64 * 32; f += 256) {
    int r = f >> 5, c4 = f & 31;
    if (r < nvalid) {
      f32x4 v = *(const f32x4*)(uo + r * US + c4 * 4);
      bf16x4 o = {(__bf16)v[0], (__bf16)v[1], (__bf16)v[2], (__bf16)v[3]};
      *(bf16x4*)(u + (size_t)(rowbase + r) * HID + c4 * 4) = o;
    }
  }
  if (t < HID) {
    float s = 0.f, sq = 0.f;
    for (int r = 0; r < nvalid; r++) {
      float v = uo[r * US + t];
      s += v;
      sq += v * v;
    }
    atomicAdd(&bnstats[t], s);
    atomicAdd(&bnstats[HID + t], sq);
  }
}

// ---------------- BN finalize: a = g*rsqrt(var+eps), b = beta - mean*a ------
__global__ __launch_bounds__(128) void bn_finalize_kernel(const float* __restrict__ bnstats,
                                                          const float* __restrict__ gamma,
                                                          const float* __restrict__ beta,
                                                          float* __restrict__ bnab) {
  int t = threadIdx.x;
  const float invN = 1.f / (float)N_NODES;
  float mean = bnstats[t] * invN;
  float var = bnstats[HID + t] * invN - mean * mean;
  float a = gamma[t] * rsqrtf(var + BN_EPS);
  bnab[t] = a;
  bnab[HID + t] = beta[t] - mean * a;
}

// ---------------- BN apply + mean-pool accumulate (layer 2, bf16 in) --------
__global__ __launch_bounds__(128) void bn_apply_pool_kernel(const __bf16* __restrict__ u,
                                                            const float* __restrict__ bnab,
                                                            const int* __restrict__ batch,
                                                            float* __restrict__ pool) {
  int c = threadIdx.x;  // feature column
  int r0 = blockIdx.x * 64;
  if (r0 >= N_NODES) return;
  int rend = min(r0 + 64, N_NODES);
  float a = bnab[c], b = bnab[HID + c];
  float accv = 0.f;
  int curg = -1;
  for (int r = r0; r < rend; r++) {
    int g = batch[r];
    if (g != curg) {
      if (curg >= 0) atomicAdd(&pool[curg * HID + c], accv);
      curg = g;
      accv = 0.f;
    }
    float v = (float)u[(size_t)r * HID + c];
    v = v * a + b;
    accv += (v > 0.f ? v : 0.f);
  }
  if (curg >= 0) atomicAdd(&pool[curg * HID + c], accv);
}

// ---------------- per-graph node counts (batch is sorted) -------------------
__global__ __launch_bounds__(256) void count_kernel(const int* __restrict__ batch,
                                                    int* __restrict__ counts) {
  int t = blockIdx.x * 256 + threadIdx.x;
  int r0 = t * 64;
  if (r0 >= N_NODES) return;
  int rend = min(r0 + 64, N_NODES);
  int curg = batch[r0], cnt = 0;
  for (int r = r0; r < rend; r++) {
    int g = batch[r];
    if (g != curg) {
      atomicAdd(&counts[curg], cnt);
      curg = g;
      cnt = 1;
    } else {
      cnt++;
    }
  }
  atomicAdd(&counts[curg], cnt);
}

// ---------------- hg = pool/cnt; out = hg @ proj_w + proj_b -----------------
__global__ __launch_bounds__(128) void pool_proj_kernel(const float* __restrict__ pool,
                                                        const int* __restrict__ counts,
                                                        const float* __restrict__ pw,
                                                        const float* __restrict__ pb,
                                                        float* __restrict__ out) {
  int g = blockIdx.x;
  int c = threadIdx.x;
  __shared__ float hg[HID];
  float cnt = (float)max(counts[g], 1);
  hg[c] = pool[g * HID + c] / cnt;
  __syncthreads();
  float acc = pb[c];
#pragma unroll 8
  for (int k = 0; k < HID; k++) acc += hg[k] * pw[k * HID + c];
  out[g * HID + c] = acc;
}

// ============================================================================
extern "C" void kernel_launch(void* const* d_in, const int* in_sizes, int n_in,
                              void* d_out, int out_size, void* d_ws, size_t ws_size,
                              hipStream_t stream) {
  (void)in_sizes; (void)n_in; (void)out_size; (void)ws_size;
  const float* x = (const float*)d_in[0];
  const int* ei = (const int*)d_in[1];
  const int* batch = (const int*)d_in[2];
  const float* w1[3] = {(const float*)d_in[3], (const float*)d_in[9], (const float*)d_in[15]};
  const float* b1[3] = {(const float*)d_in[4], (const float*)d_in[10], (const float*)d_in[16]};
  const float* w2[3] = {(const float*)d_in[5], (const float*)d_in[11], (const float*)d_in[17]};
  const float* b2[3] = {(const float*)d_in[6], (const float*)d_in[12], (const float*)d_in[18]};
  const float* gm[3] = {(const float*)d_in[7], (const float*)d_in[13], (const float*)d_in[19]};
  const float* bt[3] = {(const float*)d_in[8], (const float*)d_in[14], (const float*)d_in[20]};
  const float* pw = (const float*)d_in[21];
  const float* pb = (const float*)d_in[22];
  float* out = (float*)d_out;

  // workspace carve (ping-pong bf16 node buffers: no in-place read/write race)
  char* ws = (char*)d_ws;
  __bf16* hB0 = (__bf16*)ws;         ws += (size_t)N_NODES * HID * 2;   // 25.6 MB
  __bf16* hB1 = (__bf16*)ws;         ws += (size_t)N_NODES * HID * 2;   // 25.6 MB
  int* srcs = (int*)ws;              ws += (size_t)N_EDGES * 4;         // 6.4 MB
  int* ecounts = (int*)ws;           ws += (size_t)N_NODES * 4;
  int* starts = (int*)ws;            ws += (size_t)(N_NODES + 1) * 4;
  int* cursor = (int*)ws;            ws += (size_t)N_NODES * 4;
  int* btot = (int*)ws;              ws += SCAN_NB * 4;
  int* boff = (int*)ws;              ws += SCAN_NB * 4;
  ws = (char*)(((uintptr_t)ws + 63) & ~(uintptr_t)63);  // 16B+ align weights
  __bf16* wt_all = (__bf16*)ws;      ws += 90112 * 2;
  ws = (char*)(((uintptr_t)ws + 63) & ~(uintptr_t)63);
  float* bnstats = (float*)ws;       ws += 256 * 4;
  float* bnab = (float*)ws;          ws += 256 * 4;
  float* pool = (float*)ws;          ws += N_GRAPHS * HID * 4;          // contiguous with counts
  int* counts = (int*)ws;            ws += N_GRAPHS * 4;

  __bf16* w1t0 = wt_all;
  __bf16* w2t0 = wt_all + 8192;
  __bf16* w1t1 = wt_all + 24576;
  __bf16* w2t1 = wt_all + 40960;
  __bf16* w1t2 = wt_all + 57344;
  __bf16* w2t2 = wt_all + 73728;

  const int eblocks = (N_EDGES + 255) / 256;  // 6250
  const int mlp_blocks = (N_NODES + 63) / 64; // 1563

  // weight prep (bf16 transposed, one kernel)
  prep_all_kernel<<<(90112 + 255) / 256, 256, 0, stream>>>(
      w1[0], w2[0], w1[1], w2[1], w1[2], w2[2], wt_all);

  // CSR build: histogram -> 3-step device-wide scan -> reorder
  hipMemsetAsync(ecounts, 0, (size_t)N_NODES * 4, stream);
  hist_kernel<<<eblocks, 256, 0, stream>>>(ei, ecounts);
  local_scan_kernel<<<SCAN_NB, 256, 0, stream>>>(ecounts, starts, btot);
  scan_totals_kernel<<<1, 512, 0, stream>>>(btot, boff, starts);
  add_off_kernel<<<SCAN_NB, 256, 0, stream>>>(starts, boff, cursor);
  reorder_kernel<<<eblocks, 256, 0, stream>>>(ei, cursor, srcs);

  // zero pool + counts (contiguous), count nodes/graph
  hipMemsetAsync(pool, 0, (size_t)N_GRAPHS * HID * 4 + N_GRAPHS * 4, stream);
  count_kernel<<<((N_NODES + 63) / 64 + 255) / 256, 256, 0, stream>>>(batch, counts);

  // layer 0: x (fp32) -> hB0
  hipMemsetAsync(bnstats, 0, 256 * 4, stream);
  fused_mlp_kernel<64, false><<<mlp_blocks, 256, 0, stream>>>(
      x, starts, srcs, nullptr, w1t0, b1[0], w2t0, b2[0], hB0, bnstats);
  bn_finalize_kernel<<<1, 128, 0, stream>>>(bnstats, gm[0], bt[0], bnab);

  // layer 1: hB0 -> hB1
  hipMemsetAsync(bnstats, 0, 256 * 4, stream);
  fused_mlp_kernel<128, true><<<mlp_blocks, 256, 0, stream>>>(
      hB0, starts, srcs, bnab, w1t1, b1[1], w2t1, b2[1], hB1, bnstats);
  bn_finalize_kernel<<<1, 128, 0, stream>>>(bnstats, gm[1], bt[1], bnab);

  // layer 2: hB1 -> hB0
  hipMemsetAsync(bnstats, 0, 256 * 4, stream);
  fused_mlp_kernel<128, true><<<mlp_blocks, 256, 0, stream>>>(
      hB1, starts, srcs, bnab, w1t2, b1[2], w2t2, b2[2], hB0, bnstats);
  bn_finalize_kernel<<<1, 128, 0, stream>>>(bnstats, gm[2], bt[2], bnab);

  bn_apply_pool_kernel<<<mlp_blocks, 128, 0, stream>>>(hB0, bnab, batch, pool);

  pool_proj_kernel<<<N_GRAPHS, 128, 0, stream>>>(pool, counts, pw, pb, out);
}

// Round 6
// 785.457 us; speedup vs baseline: 9.1012x; 1.1175x over previous
//
#include <hip/hip_runtime.h>

#define N_NODES 100000
#define N_EDGES 1600000
#define N_GRAPHS 256
#define HID 128
#define BN_EPS 1e-5f

typedef __bf16 bf16x8 __attribute__((ext_vector_type(8)));
typedef __bf16 bf16x4 __attribute__((ext_vector_type(4)));
typedef __bf16 bf16x2 __attribute__((ext_vector_type(2)));
typedef float f32x4 __attribute__((ext_vector_type(4)));

#define SCAN_NB ((N_NODES + 255) / 256)  // 391

// ---------------- weight prep: all 6 weights -> one bf16 transposed buffer --
__global__ __launch_bounds__(256) void prep_all_kernel(
    const float* __restrict__ wa, const float* __restrict__ wb,
    const float* __restrict__ wc, const float* __restrict__ wd,
    const float* __restrict__ we, const float* __restrict__ wf,
    __bf16* __restrict__ wt) {
  int idx = blockIdx.x * 256 + threadIdx.x;
  if (idx >= 90112) return;
  const float* w;
  int K, local;
  if (idx < 8192) { w = wa; K = 64; local = idx; }
  else {
    int s = (idx - 8192) / 16384;
    local = (idx - 8192) - s * 16384;
    K = 128;
    w = (s == 0) ? wb : (s == 1) ? wc : (s == 2) ? wd : (s == 3) ? we : wf;
  }
  int n = local / K, k = local - n * K;
  wt[idx] = (__bf16)w[k * 128 + n];
}

// ---------------- CSR build: histogram of dst ------------------------------
__global__ __launch_bounds__(256) void hist_kernel(const int* __restrict__ ei,
                                                   int* __restrict__ counts) {
  int e = blockIdx.x * 256 + threadIdx.x;
  if (e < N_EDGES) atomicAdd(&counts[ei[N_EDGES + e]], 1);
}

// ---------------- scan step 1: per-block local exclusive scan ---------------
__global__ __launch_bounds__(256) void local_scan_kernel(const int* __restrict__ counts,
                                                         int* __restrict__ starts,
                                                         int* __restrict__ btot) {
  __shared__ int ps[256];
  int t = threadIdx.x;
  int i = blockIdx.x * 256 + t;
  int c = (i < N_NODES) ? counts[i] : 0;
  ps[t] = c;
  __syncthreads();
  for (int off = 1; off < 256; off <<= 1) {
    int v = ps[t];
    int u = (t >= off) ? ps[t - off] : 0;
    __syncthreads();
    ps[t] = v + u;
    __syncthreads();
  }
  if (i < N_NODES) starts[i] = ps[t] - c;  // local exclusive
  if (t == 255) btot[blockIdx.x] = ps[255];
}

// ---------------- scan step 2: scan the 391 block totals --------------------
__global__ __launch_bounds__(512) void scan_totals_kernel(const int* __restrict__ btot,
                                                          int* __restrict__ boff,
                                                          int* __restrict__ starts) {
  __shared__ int ps[512];
  int t = threadIdx.x;
  int v = (t < SCAN_NB) ? btot[t] : 0;
  ps[t] = v;
  __syncthreads();
  for (int off = 1; off < 512; off <<= 1) {
    int a = ps[t];
    int u = (t >= off) ? ps[t - off] : 0;
    __syncthreads();
    ps[t] = a + u;
    __syncthreads();
  }
  if (t < SCAN_NB) boff[t] = ps[t] - v;  // exclusive
  if (t == 511) starts[N_NODES] = ps[511];
}

// ---------------- scan step 3: add offsets, write starts + cursor -----------
__global__ __launch_bounds__(256) void add_off_kernel(int* __restrict__ starts,
                                                      const int* __restrict__ boff,
                                                      int* __restrict__ cursor) {
  int i = blockIdx.x * 256 + threadIdx.x;
  if (i >= N_NODES) return;
  int v = starts[i] + boff[blockIdx.x];
  starts[i] = v;
  cursor[i] = v;
}

// ---------------- CSR build: reorder src by dst bucket ----------------------
__global__ __launch_bounds__(256) void reorder_kernel(const int* __restrict__ ei,
                                                      int* __restrict__ cursor,
                                                      int* __restrict__ srcs) {
  int e = blockIdx.x * 256 + threadIdx.x;
  if (e >= N_EDGES) return;
  int dst = ei[N_EDGES + e];
  int pos = atomicAdd(&cursor[dst], 1);
  srcs[pos] = ei[e];
}

// ---------------- h = relu(a*u + b) elementwise, bf16 -> bf16 ---------------
__global__ __launch_bounds__(256) void h_apply_kernel(const __bf16* __restrict__ u,
                                                      const float* __restrict__ bnab,
                                                      __bf16* __restrict__ h) {
  int idx = blockIdx.x * 256 + threadIdx.x;  // chunk of 8 elems
  if (idx >= N_NODES * (HID / 8)) return;
  int c8 = idx & 15;  // chunk within row
  bf16x8 v = ((const bf16x8*)u)[idx];
  f32x4 a0 = ((const f32x4*)bnab)[c8 * 2];
  f32x4 a1 = ((const f32x4*)bnab)[c8 * 2 + 1];
  f32x4 b0 = ((const f32x4*)(bnab + HID))[c8 * 2];
  f32x4 b1 = ((const f32x4*)(bnab + HID))[c8 * 2 + 1];
  bf16x8 o;
#pragma unroll
  for (int k = 0; k < 4; k++) {
    o[k] = (__bf16)fmaxf(fmaf(a0[k], (float)v[k], b0[k]), 0.f);
    o[4 + k] = (__bf16)fmaxf(fmaf(a1[k], (float)v[4 + k], b1[k]), 0.f);
  }
  ((bf16x8*)h)[idx] = o;
}

// ---------------- gather: z[row] = h[row] + sum_{CSR[row]} h[src] -----------
// One wave per row; zero LDS; 8 gather loads in flight per wave.
template <int C, typename T>
__global__ __launch_bounds__(256) void gather_kernel(const T* __restrict__ h,
                                                     const int* __restrict__ starts,
                                                     const int* __restrict__ srcs,
                                                     __bf16* __restrict__ z) {
  const int lane = threadIdx.x & 63;
  const int row = blockIdx.x * 4 + (threadIdx.x >> 6);
  if (row >= N_NODES) return;
  int e0 = starts[row], e1 = starts[row + 1];
  int deg = e1 - e0;
  int idxv = srcs[min(e0 + lane, N_EDGES - 1)];
  int dcap = min(deg, 64);
  if constexpr (C == 64) {
    float acc = h[(size_t)row * 64 + lane];
    float s0 = 0.f, s1 = 0.f, s2 = 0.f, s3 = 0.f, s4 = 0.f, s5 = 0.f, s6 = 0.f, s7 = 0.f;
    int j = 0;
    for (; j + 7 < dcap; j += 8) {
      int i0 = __builtin_amdgcn_readlane(idxv, j);
      int i1 = __builtin_amdgcn_readlane(idxv, j + 1);
      int i2 = __builtin_amdgcn_readlane(idxv, j + 2);
      int i3 = __builtin_amdgcn_readlane(idxv, j + 3);
      int i4 = __builtin_amdgcn_readlane(idxv, j + 4);
      int i5 = __builtin_amdgcn_readlane(idxv, j + 5);
      int i6 = __builtin_amdgcn_readlane(idxv, j + 6);
      int i7 = __builtin_amdgcn_readlane(idxv, j + 7);
      float v0 = h[(size_t)i0 * 64 + lane];
      float v1 = h[(size_t)i1 * 64 + lane];
      float v2 = h[(size_t)i2 * 64 + lane];
      float v3 = h[(size_t)i3 * 64 + lane];
      float v4 = h[(size_t)i4 * 64 + lane];
      float v5 = h[(size_t)i5 * 64 + lane];
      float v6 = h[(size_t)i6 * 64 + lane];
      float v7 = h[(size_t)i7 * 64 + lane];
      s0 += v0; s1 += v1; s2 += v2; s3 += v3;
      s4 += v4; s5 += v5; s6 += v6; s7 += v7;
    }
    for (; j < dcap; j++) {
      int i0 = __builtin_amdgcn_readlane(idxv, j);
      s0 += h[(size_t)i0 * 64 + lane];
    }
    for (int e = e0 + 64; e < e1; e++) s0 += h[(size_t)srcs[e] * 64 + lane];
    acc += ((s0 + s1) + (s2 + s3)) + ((s4 + s5) + (s6 + s7));
    z[(size_t)row * 64 + lane] = (__bf16)acc;
  } else {
    const __bf16* hb = (const __bf16*)h;
    bf16x2 sv = *(const bf16x2*)(hb + (size_t)row * 128 + lane * 2);
    float ax = (float)sv[0], ay = (float)sv[1];
    float2 s0 = {0.f, 0.f}, s1 = {0.f, 0.f}, s2 = {0.f, 0.f}, s3 = {0.f, 0.f};
    float2 s4 = {0.f, 0.f}, s5 = {0.f, 0.f}, s6 = {0.f, 0.f}, s7 = {0.f, 0.f};
    int j = 0;
    for (; j + 7 < dcap; j += 8) {
      int i0 = __builtin_amdgcn_readlane(idxv, j);
      int i1 = __builtin_amdgcn_readlane(idxv, j + 1);
      int i2 = __builtin_amdgcn_readlane(idxv, j + 2);
      int i3 = __builtin_amdgcn_readlane(idxv, j + 3);
      int i4 = __builtin_amdgcn_readlane(idxv, j + 4);
      int i5 = __builtin_amdgcn_readlane(idxv, j + 5);
      int i6 = __builtin_amdgcn_readlane(idxv, j + 6);
      int i7 = __builtin_amdgcn_readlane(idxv, j + 7);
      bf16x2 v0 = *(const bf16x2*)(hb + (size_t)i0 * 128 + lane * 2);
      bf16x2 v1 = *(const bf16x2*)(hb + (size_t)i1 * 128 + lane * 2);
      bf16x2 v2 = *(const bf16x2*)(hb + (size_t)i2 * 128 + lane * 2);
      bf16x2 v3 = *(const bf16x2*)(hb + (size_t)i3 * 128 + lane * 2);
      bf16x2 v4 = *(const bf16x2*)(hb + (size_t)i4 * 128 + lane * 2);
      bf16x2 v5 = *(const bf16x2*)(hb + (size_t)i5 * 128 + lane * 2);
      bf16x2 v6 = *(const bf16x2*)(hb + (size_t)i6 * 128 + lane * 2);
      bf16x2 v7 = *(const bf16x2*)(hb + (size_t)i7 * 128 + lane * 2);
      s0.x += (float)v0[0]; s0.y += (float)v0[1];
      s1.x += (float)v1[0]; s1.y += (float)v1[1];
      s2.x += (float)v2[0]; s2.y += (float)v2[1];
      s3.x += (float)v3[0]; s3.y += (float)v3[1];
      s4.x += (float)v4[0]; s4.y += (float)v4[1];
      s5.x += (float)v5[0]; s5.y += (float)v5[1];
      s6.x += (float)v6[0]; s6.y += (float)v6[1];
      s7.x += (float)v7[0]; s7.y += (float)v7[1];
    }
    for (; j < dcap; j++) {
      int i0 = __builtin_amdgcn_readlane(idxv, j);
      bf16x2 vv = *(const bf16x2*)(hb + (size_t)i0 * 128 + lane * 2);
      s0.x += (float)vv[0]; s0.y += (float)vv[1];
    }
    for (int e = e0 + 64; e < e1; e++) {
      bf16x2 vv = *(const bf16x2*)(hb + (size_t)srcs[e] * 128 + lane * 2);
      s0.x += (float)vv[0]; s0.y += (float)vv[1];
    }
    ax += ((s0.x + s1.x) + (s2.x + s3.x)) + ((s4.x + s5.x) + (s6.x + s7.x));
    ay += ((s0.y + s1.y) + (s2.y + s3.y)) + ((s4.y + s5.y) + (s6.y + s7.y));
    bf16x2 z2 = {(__bf16)ax, (__bf16)ay};
    *(bf16x2*)(z + (size_t)row * 128 + lane * 2) = z2;
  }
}

// ---------------- dense MLP: u = relu(z@W1+b1)@W2+b2 + BN partials ----------
// Block-local: reads its own 64 z rows, writes same 64 u rows (in-place safe).
template <int CIN>
__global__ __launch_bounds__(256) void mlp_kernel(
    const __bf16* __restrict__ z, const __bf16* __restrict__ w1t,
    const float* __restrict__ b1, const __bf16* __restrict__ w2t,
    const float* __restrict__ b2, __bf16* __restrict__ u,
    float* __restrict__ bnstats) {
  constexpr int ZS = CIN + 8;   // bf16 elems/row (+pad); byte stride 16-aligned
  constexpr int TS = HID + 8;
  constexpr int US = 132;
  constexpr int ZB = 64 * ZS * 2;
  constexpr int TB = 64 * TS * 2;
  constexpr int UB = 64 * US * 4;
  constexpr int SB = (ZB + TB) > UB ? (ZB + TB) : UB;
  __shared__ __align__(16) char smem[SB];
  __bf16* zt = (__bf16*)smem;
  __bf16* tt = (__bf16*)(smem + ZB);

  const int t = threadIdx.x;
  const int wave = t >> 6;
  const int lane = t & 63;
  const int l16 = lane & 15;
  const int quad = lane >> 4;
  const int rowbase = blockIdx.x * 64;
  const int nvalid = min(64, N_NODES - rowbase);

  // Phase A: coalesced global -> LDS staging of z (bf16x8 chunks)
  {
    constexpr int CH = CIN / 8;
    const bf16x8 zero8 = {};
    for (int f = t; f < 64 * CH; f += 256) {
      int r = f / CH, c = f - r * CH;
      int gr = rowbase + r;
      bf16x8 v = (gr < N_NODES) ? *(const bf16x8*)(z + (size_t)gr * CIN + c * 8) : zero8;
      *(bf16x8*)(zt + r * ZS + c * 8) = v;
    }
  }
  __syncthreads();

  const f32x4 zero4 = {0.f, 0.f, 0.f, 0.f};
  f32x4 acc[8];

  // Phase B: t = relu(z @ W1 + b1) -> LDS (bf16)
  {
#pragma unroll
    for (int ct = 0; ct < 8; ct++) acc[ct] = zero4;
    const __bf16* arow = zt + (wave * 16 + l16) * ZS + quad * 8;
#pragma unroll
    for (int ks = 0; ks < CIN / 32; ks++) {
      bf16x8 af = *(const bf16x8*)(arow + ks * 32);
#pragma unroll
      for (int ct = 0; ct < 8; ct++) {
        bf16x8 bfr = *(const bf16x8*)(w1t + (ct * 16 + l16) * CIN + ks * 32 + quad * 8);
        acc[ct] = __builtin_amdgcn_mfma_f32_16x16x32_bf16(af, bfr, acc[ct], 0, 0, 0);
      }
    }
#pragma unroll
    for (int ct = 0; ct < 8; ct++) {
      int col = ct * 16 + l16;
      float bias = b1[col];
#pragma unroll
      for (int r = 0; r < 4; r++) {
        float v = acc[ct][r] + bias;
        tt[(wave * 16 + quad * 4 + r) * TS + col] = (__bf16)(v > 0.f ? v : 0.f);
      }
    }
  }
  __syncthreads();

  // Phase C: u = t @ W2 + b2
  {
#pragma unroll
    for (int ct = 0; ct < 8; ct++) acc[ct] = zero4;
    const __bf16* arow = tt + (wave * 16 + l16) * TS + quad * 8;
#pragma unroll
    for (int ks = 0; ks < HID / 32; ks++) {
      bf16x8 af = *(const bf16x8*)(arow + ks * 32);
#pragma unroll
      for (int ct = 0; ct < 8; ct++) {
        bf16x8 bfr = *(const bf16x8*)(w2t + (ct * 16 + l16) * HID + ks * 32 + quad * 8);
        acc[ct] = __builtin_amdgcn_mfma_f32_16x16x32_bf16(af, bfr, acc[ct], 0, 0, 0);
      }
    }
  }
  __syncthreads();  // all tt reads done; reuse smem as fp32 u tile
  float* uo = (float*)smem;
#pragma unroll
  for (int ct = 0; ct < 8; ct++) {
    int col = ct * 16 + l16;
    float bias = b2[col];
#pragma unroll
    for (int r = 0; r < 4; r++) {
      uo[(wave * 16 + quad * 4 + r) * US + col] = acc[ct][r] + bias;
    }
  }
  __syncthreads();

  // coalesced bf16 global store of u + per-block BN partial sums (fp32)
  for (int f = t; f < 64 * 32; f += 256) {
    int r = f >> 5, c4 = f & 31;
    if (r < nvalid) {
      f32x4 v = *(const f32x4*)(uo + r * US + c4 * 4);
      bf16x4 o = {(__bf16)v[0], (__bf16)v[1], (__bf16)v[2], (__bf16)v[3]};
      *(bf16x4*)(u + (size_t)(rowbase + r) * HID + c4 * 4) = o;
    }
  }
  if (t < HID) {
    float s = 0.f, sq = 0.f;
    for (int r = 0; r < nvalid; r++) {
      float v = uo[r * US + t];
      s += v;
      sq += v * v;
    }
    atomicAdd(&bnstats[t], s);
    atomicAdd(&bnstats[HID + t], sq);
  }
}

// ---------------- BN finalize: a = g*rsqrt(var+eps), b = beta - mean*a ------
__global__ __launch_bounds__(128) void bn_finalize_kernel(const float* __restrict__ bnstats,
                                                          const float* __restrict__ gamma,
                                                          const float* __restrict__ beta,
                                                          float* __restrict__ bnab) {
  int t = threadIdx.x;
  const float invN = 1.f / (float)N_NODES;
  float mean = bnstats[t] * invN;
  float var = bnstats[HID + t] * invN - mean * mean;
  float a = gamma[t] * rsqrtf(var + BN_EPS);
  bnab[t] = a;
  bnab[HID + t] = beta[t] - mean * a;
}

// ---------------- BN apply + mean-pool accumulate (layer 2, bf16 in) --------
__global__ __launch_bounds__(128) void bn_apply_pool_kernel(const __bf16* __restrict__ u,
                                                            const float* __restrict__ bnab,
                                                            const int* __restrict__ batch,
                                                            float* __restrict__ pool) {
  int c = threadIdx.x;  // feature column
  int r0 = blockIdx.x * 64;
  if (r0 >= N_NODES) return;
  int rend = min(r0 + 64, N_NODES);
  float a = bnab[c], b = bnab[HID + c];
  float accv = 0.f;
  int curg = -1;
  for (int r = r0; r < rend; r++) {
    int g = batch[r];
    if (g != curg) {
      if (curg >= 0) atomicAdd(&pool[curg * HID + c], accv);
      curg = g;
      accv = 0.f;
    }
    float v = (float)u[(size_t)r * HID + c];
    v = v * a + b;
    accv += (v > 0.f ? v : 0.f);
  }
  if (curg >= 0) atomicAdd(&pool[curg * HID + c], accv);
}

// ---------------- per-graph node counts (batch is sorted) -------------------
__global__ __launch_bounds__(256) void count_kernel(const int* __restrict__ batch,
                                                    int* __restrict__ counts) {
  int t = blockIdx.x * 256 + threadIdx.x;
  int r0 = t * 64;
  if (r0 >= N_NODES) return;
  int rend = min(r0 + 64, N_NODES);
  int curg = batch[r0], cnt = 0;
  for (int r = r0; r < rend; r++) {
    int g = batch[r];
    if (g != curg) {
      atomicAdd(&counts[curg], cnt);
      curg = g;
      cnt = 1;
    } else {
      cnt++;
    }
  }
  atomicAdd(&counts[curg], cnt);
}

// ---------------- hg = pool/cnt; out = hg @ proj_w + proj_b -----------------
__global__ __launch_bounds__(128) void pool_proj_kernel(const float* __restrict__ pool,
                                                        const int* __restrict__ counts,
                                                        const float* __restrict__ pw,
                                                        const float* __restrict__ pb,
                                                        float* __restrict__ out) {
  int g = blockIdx.x;
  int c = threadIdx.x;
  __shared__ float hg[HID];
  float cnt = (float)max(counts[g], 1);
  hg[c] = pool[g * HID + c] / cnt;
  __syncthreads();
  float acc = pb[c];
#pragma unroll 8
  for (int k = 0; k < HID; k++) acc += hg[k] * pw[k * HID + c];
  out[g * HID + c] = acc;
}

// ============================================================================
extern "C" void kernel_launch(void* const* d_in, const int* in_sizes, int n_in,
                              void* d_out, int out_size, void* d_ws, size_t ws_size,
                              hipStream_t stream) {
  (void)in_sizes; (void)n_in; (void)out_size; (void)ws_size;
  const float* x = (const float*)d_in[0];
  const int* ei = (const int*)d_in[1];
  const int* batch = (const int*)d_in[2];
  const float* w1[3] = {(const float*)d_in[3], (const float*)d_in[9], (const float*)d_in[15]};
  const float* b1[3] = {(const float*)d_in[4], (const float*)d_in[10], (const float*)d_in[16]};
  const float* w2[3] = {(const float*)d_in[5], (const float*)d_in[11], (const float*)d_in[17]};
  const float* b2[3] = {(const float*)d_in[6], (const float*)d_in[12], (const float*)d_in[18]};
  const float* gm[3] = {(const float*)d_in[7], (const float*)d_in[13], (const float*)d_in[19]};
  const float* bt[3] = {(const float*)d_in[8], (const float*)d_in[14], (const float*)d_in[20]};
  const float* pw = (const float*)d_in[21];
  const float* pb = (const float*)d_in[22];
  float* out = (float*)d_out;

  // workspace carve
  char* ws = (char*)d_ws;
  __bf16* bufA = (__bf16*)ws;        ws += (size_t)N_NODES * HID * 2;   // 25.6 MB
  __bf16* bufB = (__bf16*)ws;        ws += (size_t)N_NODES * HID * 2;   // 25.6 MB
  __bf16* bufC = (__bf16*)ws;        ws += (size_t)N_NODES * HID * 2;   // 25.6 MB
  __bf16* z0 = (__bf16*)ws;          ws += (size_t)N_NODES * 64 * 2;    // 12.8 MB
  int* srcs = (int*)ws;              ws += (size_t)N_EDGES * 4;         // 6.4 MB
  int* ecounts = (int*)ws;           ws += (size_t)N_NODES * 4;
  int* starts = (int*)ws;            ws += (size_t)(N_NODES + 1) * 4;
  int* cursor = (int*)ws;            ws += (size_t)N_NODES * 4;
  int* btot = (int*)ws;              ws += SCAN_NB * 4;
  int* boff = (int*)ws;              ws += SCAN_NB * 4;
  ws = (char*)(((uintptr_t)ws + 63) & ~(uintptr_t)63);
  __bf16* wt_all = (__bf16*)ws;      ws += 90112 * 2;
  ws = (char*)(((uintptr_t)ws + 63) & ~(uintptr_t)63);
  float* bnstats = (float*)ws;       ws += 256 * 4;
  float* bnab = (float*)ws;          ws += 256 * 4;
  float* pool = (float*)ws;          ws += N_GRAPHS * HID * 4;          // contiguous with counts
  int* counts = (int*)ws;            ws += N_GRAPHS * 4;

  __bf16* w1t0 = wt_all;
  __bf16* w2t0 = wt_all + 8192;
  __bf16* w1t1 = wt_all + 24576;
  __bf16* w2t1 = wt_all + 40960;
  __bf16* w1t2 = wt_all + 57344;
  __bf16* w2t2 = wt_all + 73728;

  const int eblocks = (N_EDGES + 255) / 256;   // 6250
  const int mlp_blocks = (N_NODES + 63) / 64;  // 1563
  const int gat_blocks = (N_NODES + 3) / 4;    // 25000
  const int app_blocks = (N_NODES * (HID / 8) + 255) / 256;  // 6250

  // weight prep (bf16 transposed, one kernel)
  prep_all_kernel<<<(90112 + 255) / 256, 256, 0, stream>>>(
      w1[0], w2[0], w1[1], w2[1], w1[2], w2[2], wt_all);

  // CSR build: histogram -> 3-step device-wide scan -> reorder
  hipMemsetAsync(ecounts, 0, (size_t)N_NODES * 4, stream);
  hist_kernel<<<eblocks, 256, 0, stream>>>(ei, ecounts);
  local_scan_kernel<<<SCAN_NB, 256, 0, stream>>>(ecounts, starts, btot);
  scan_totals_kernel<<<1, 512, 0, stream>>>(btot, boff, starts);
  add_off_kernel<<<SCAN_NB, 256, 0, stream>>>(starts, boff, cursor);
  reorder_kernel<<<eblocks, 256, 0, stream>>>(ei, cursor, srcs);

  // zero pool + counts (contiguous), count nodes/graph
  hipMemsetAsync(pool, 0, (size_t)N_GRAPHS * HID * 4 + N_GRAPHS * 4, stream);
  count_kernel<<<((N_NODES + 63) / 64 + 255) / 256, 256, 0, stream>>>(batch, counts);

  // layer 0: gather(x fp32) -> z0; mlp64: z0 -> bufA (u0)
  hipMemsetAsync(bnstats, 0, 256 * 4, stream);
  gather_kernel<64, float><<<gat_blocks, 256, 0, stream>>>(x, starts, srcs, z0);
  mlp_kernel<64><<<mlp_blocks, 256, 0, stream>>>(z0, w1t0, b1[0], w2t0, b2[0], bufA, bnstats);
  bn_finalize_kernel<<<1, 128, 0, stream>>>(bnstats, gm[0], bt[0], bnab);

  // layer 1: h1 = relu(a*u0+b) -> bufB; gather -> bufC; mlp -> bufC in place
  hipMemsetAsync(bnstats, 0, 256 * 4, stream);
  h_apply_kernel<<<app_blocks, 256, 0, stream>>>(bufA, bnab, bufB);
  gather_kernel<128, __bf16><<<gat_blocks, 256, 0, stream>>>(bufB, starts, srcs, bufC);
  mlp_kernel<128><<<mlp_blocks, 256, 0, stream>>>(bufC, w1t1, b1[1], w2t1, b2[1], bufC, bnstats);
  bn_finalize_kernel<<<1, 128, 0, stream>>>(bnstats, gm[1], bt[1], bnab);

  // layer 2: h2 -> bufA; gather -> bufB; mlp -> bufB in place
  hipMemsetAsync(bnstats, 0, 256 * 4, stream);
  h_apply_kernel<<<app_blocks, 256, 0, stream>>>(bufC, bnab, bufA);
  gather_kernel<128, __bf16><<<gat_blocks, 256, 0, stream>>>(bufA, starts, srcs, bufB);
  mlp_kernel<128><<<mlp_blocks, 256, 0, stream>>>(bufB, w1t2, b1[2], w2t2, b2[2], bufB, bnstats);
  bn_finalize_kernel<<<1, 128, 0, stream>>>(bnstats, gm[2], bt[2], bnab);

  bn_apply_pool_kernel<<<mlp_blocks, 128, 0, stream>>>(bufB, bnab, batch, pool);

  pool_proj_kernel<<<N_GRAPHS, 128, 0, stream>>>(pool, counts, pw, pb, out);
}

// Round 7
// 635.582 us; speedup vs baseline: 11.2473x; 1.2358x over previous
//
#include <hip/hip_runtime.h>

#define N_NODES 100000
#define N_EDGES 1600000
#define N_GRAPHS 256
#define HID 128
#define BN_EPS 1e-5f

#define NT 1563        // ceil(N_NODES/64) tile buckets
#define EB 16384       // edges per reorder block
#define RB 98          // ceil(N_EDGES/EB)

typedef __bf16 bf16x8 __attribute__((ext_vector_type(8)));
typedef __bf16 bf16x4 __attribute__((ext_vector_type(4)));
typedef __bf16 bf16x2 __attribute__((ext_vector_type(2)));
typedef float f32x4 __attribute__((ext_vector_type(4)));

// ---------------- weight prep: all 6 weights -> one bf16 transposed buffer --
__global__ __launch_bounds__(256) void prep_all_kernel(
    const float* __restrict__ wa, const float* __restrict__ wb,
    const float* __restrict__ wc, const float* __restrict__ wd,
    const float* __restrict__ we, const float* __restrict__ wf,
    __bf16* __restrict__ wt) {
  int idx = blockIdx.x * 256 + threadIdx.x;
  if (idx >= 90112) return;
  const float* w;
  int K, local;
  if (idx < 8192) { w = wa; K = 64; local = idx; }
  else {
    int s = (idx - 8192) / 16384;
    local = (idx - 8192) - s * 16384;
    K = 128;
    w = (s == 0) ? wb : (s == 1) ? wc : (s == 2) ? wd : (s == 3) ? we : wf;
  }
  int n = local / K, k = local - n * K;
  wt[idx] = (__bf16)w[k * 128 + n];
}

// ---------------- CSR stage 1: tile-bucket histogram (LDS-staged) -----------
__global__ __launch_bounds__(256) void tile_hist_kernel(const int* __restrict__ ei,
                                                        int* __restrict__ tcnt) {
  __shared__ int hist[NT];
  int t = threadIdx.x;
  for (int i = t; i < NT; i += 256) hist[i] = 0;
  __syncthreads();
  int base = blockIdx.x * EB;
#pragma unroll 4
  for (int i = 0; i < EB / 256; i++) {
    int e = base + i * 256 + t;
    if (e < N_EDGES) atomicAdd(&hist[ei[N_EDGES + e] >> 6], 1);
  }
  __syncthreads();
  for (int i = t; i < NT; i += 256) {
    int h = hist[i];
    if (h) atomicAdd(&tcnt[i], h);
  }
}

// ---------------- CSR stage 2: scan 1563 tile counts ------------------------
__global__ __launch_bounds__(256) void tile_scan_kernel(const int* __restrict__ tcnt,
                                                        int* __restrict__ tstart,
                                                        int* __restrict__ gcursor) {
  __shared__ int ps[256];
  int t = threadIdx.x;
  const int CH = (NT + 255) / 256;  // 7
  int lo = t * CH, hi = min(lo + CH, NT);
  int s = 0;
  for (int i = lo; i < hi; i++) s += tcnt[i];
  ps[t] = s;
  __syncthreads();
  for (int off = 1; off < 256; off <<= 1) {
    int v = ps[t];
    int u = (t >= off) ? ps[t - off] : 0;
    __syncthreads();
    ps[t] = v + u;
    __syncthreads();
  }
  int base = (t == 0) ? 0 : ps[t - 1];
  for (int i = lo; i < hi; i++) {
    tstart[i] = base;
    gcursor[i] = base;
    base += tcnt[i];
  }
  if (t == 0) tstart[NT] = N_EDGES;
}

// ---------------- CSR stage 3: scatter into tile buckets (local writes) -----
// pack = src*64 + local_row. Per-(block,bucket) contiguous reservation keeps
// writes spatially+temporally local -> no 16x line amplification.
__global__ __launch_bounds__(256) void reorder2_kernel(const int* __restrict__ ei,
                                                       int* __restrict__ gcursor,
                                                       int* __restrict__ epack) {
  __shared__ int hist[NT];
  int t = threadIdx.x;
  for (int i = t; i < NT; i += 256) hist[i] = 0;
  __syncthreads();
  int base = blockIdx.x * EB;
#pragma unroll 4
  for (int i = 0; i < EB / 256; i++) {
    int e = base + i * 256 + t;
    if (e < N_EDGES) atomicAdd(&hist[ei[N_EDGES + e] >> 6], 1);
  }
  __syncthreads();
  for (int i = t; i < NT; i += 256) {
    int h = hist[i];
    if (h) hist[i] = atomicAdd(&gcursor[i], h);
  }
  __syncthreads();
#pragma unroll 4
  for (int i = 0; i < EB / 256; i++) {
    int e = base + i * 256 + t;
    if (e < N_EDGES) {
      int d = ei[N_EDGES + e];
      int s = ei[e];
      int pos = atomicAdd(&hist[d >> 6], 1);
      epack[pos] = (s << 6) | (d & 63);
    }
  }
}

// ---------------- CSR stage 4: per-tile counting sort -> row CSR ------------
// Block b owns epack[ts,te); all writes land in its own segment (local).
__global__ __launch_bounds__(256) void row_sort_kernel(const int* __restrict__ tstart,
                                                       const int* __restrict__ epack,
                                                       int* __restrict__ starts,
                                                       int* __restrict__ srcs) {
  __shared__ int cnt[64];
  __shared__ int rbase[65];
  __shared__ int rofs[64];
  int t = threadIdx.x, b = blockIdx.x;
  int ts = tstart[b], te = tstart[b + 1];
  if (t < 64) cnt[t] = 0;
  __syncthreads();
  for (int i = ts + t; i < te; i += 256) atomicAdd(&cnt[epack[i] & 63], 1);
  __syncthreads();
  if (t == 0) {
    int a = 0;
    for (int r = 0; r < 64; r++) { rbase[r] = a; a += cnt[r]; }
    rbase[64] = a;
  }
  __syncthreads();
  if (t < 64) rofs[t] = ts + rbase[t];
  if (t <= 64) {
    int gr = b * 64 + t;
    if (gr <= N_NODES) starts[gr] = ts + rbase[t];
  }
  __syncthreads();
  for (int i = ts + t; i < te; i += 256) {
    int p = epack[i];
    int pos = atomicAdd(&rofs[p & 63], 1);
    srcs[pos] = p >> 6;
  }
}

// ---------------- h = relu(a*u + b) elementwise, bf16 -> bf16 ---------------
__global__ __launch_bounds__(256) void h_apply_kernel(const __bf16* __restrict__ u,
                                                      const float* __restrict__ bnab,
                                                      __bf16* __restrict__ h) {
  int idx = blockIdx.x * 256 + threadIdx.x;  // chunk of 8 elems
  if (idx >= N_NODES * (HID / 8)) return;
  int c8 = idx & 15;  // chunk within row
  bf16x8 v = ((const bf16x8*)u)[idx];
  f32x4 a0 = ((const f32x4*)bnab)[c8 * 2];
  f32x4 a1 = ((const f32x4*)bnab)[c8 * 2 + 1];
  f32x4 b0 = ((const f32x4*)(bnab + HID))[c8 * 2];
  f32x4 b1 = ((const f32x4*)(bnab + HID))[c8 * 2 + 1];
  bf16x8 o;
#pragma unroll
  for (int k = 0; k < 4; k++) {
    o[k] = (__bf16)fmaxf(fmaf(a0[k], (float)v[k], b0[k]), 0.f);
    o[4 + k] = (__bf16)fmaxf(fmaf(a1[k], (float)v[4 + k], b1[k]), 0.f);
  }
  ((bf16x8*)h)[idx] = o;
}

// ---------------- gather: z[row] = h[row] + sum_{CSR[row]} h[src] -----------
// One wave per row; zero LDS; 8 gather loads in flight per wave.
template <int C, typename T>
__global__ __launch_bounds__(256) void gather_kernel(const T* __restrict__ h,
                                                     const int* __restrict__ starts,
                                                     const int* __restrict__ srcs,
                                                     __bf16* __restrict__ z) {
  const int lane = threadIdx.x & 63;
  const int row = blockIdx.x * 4 + (threadIdx.x >> 6);
  if (row >= N_NODES) return;
  int e0 = starts[row], e1 = starts[row + 1];
  int deg = e1 - e0;
  int idxv = srcs[min(e0 + lane, N_EDGES - 1)];
  int dcap = min(deg, 64);
  if constexpr (C == 64) {
    float acc = h[(size_t)row * 64 + lane];
    float s0 = 0.f, s1 = 0.f, s2 = 0.f, s3 = 0.f, s4 = 0.f, s5 = 0.f, s6 = 0.f, s7 = 0.f;
    int j = 0;
    for (; j + 7 < dcap; j += 8) {
      int i0 = __builtin_amdgcn_readlane(idxv, j);
      int i1 = __builtin_amdgcn_readlane(idxv, j + 1);
      int i2 = __builtin_amdgcn_readlane(idxv, j + 2);
      int i3 = __builtin_amdgcn_readlane(idxv, j + 3);
      int i4 = __builtin_amdgcn_readlane(idxv, j + 4);
      int i5 = __builtin_amdgcn_readlane(idxv, j + 5);
      int i6 = __builtin_amdgcn_readlane(idxv, j + 6);
      int i7 = __builtin_amdgcn_readlane(idxv, j + 7);
      float v0 = h[(size_t)i0 * 64 + lane];
      float v1 = h[(size_t)i1 * 64 + lane];
      float v2 = h[(size_t)i2 * 64 + lane];
      float v3 = h[(size_t)i3 * 64 + lane];
      float v4 = h[(size_t)i4 * 64 + lane];
      float v5 = h[(size_t)i5 * 64 + lane];
      float v6 = h[(size_t)i6 * 64 + lane];
      float v7 = h[(size_t)i7 * 64 + lane];
      s0 += v0; s1 += v1; s2 += v2; s3 += v3;
      s4 += v4; s5 += v5; s6 += v6; s7 += v7;
    }
    for (; j < dcap; j++) {
      int i0 = __builtin_amdgcn_readlane(idxv, j);
      s0 += h[(size_t)i0 * 64 + lane];
    }
    for (int e = e0 + 64; e < e1; e++) s0 += h[(size_t)srcs[e] * 64 + lane];
    acc += ((s0 + s1) + (s2 + s3)) + ((s4 + s5) + (s6 + s7));
    z[(size_t)row * 64 + lane] = (__bf16)acc;
  } else {
    const __bf16* hb = (const __bf16*)h;
    bf16x2 sv = *(const bf16x2*)(hb + (size_t)row * 128 + lane * 2);
    float ax = (float)sv[0], ay = (float)sv[1];
    float2 s0 = {0.f, 0.f}, s1 = {0.f, 0.f}, s2 = {0.f, 0.f}, s3 = {0.f, 0.f};
    float2 s4 = {0.f, 0.f}, s5 = {0.f, 0.f}, s6 = {0.f, 0.f}, s7 = {0.f, 0.f};
    int j = 0;
    for (; j + 7 < dcap; j += 8) {
      int i0 = __builtin_amdgcn_readlane(idxv, j);
      int i1 = __builtin_amdgcn_readlane(idxv, j + 1);
      int i2 = __builtin_amdgcn_readlane(idxv, j + 2);
      int i3 = __builtin_amdgcn_readlane(idxv, j + 3);
      int i4 = __builtin_amdgcn_readlane(idxv, j + 4);
      int i5 = __builtin_amdgcn_readlane(idxv, j + 5);
      int i6 = __builtin_amdgcn_readlane(idxv, j + 6);
      int i7 = __builtin_amdgcn_readlane(idxv, j + 7);
      bf16x2 v0 = *(const bf16x2*)(hb + (size_t)i0 * 128 + lane * 2);
      bf16x2 v1 = *(const bf16x2*)(hb + (size_t)i1 * 128 + lane * 2);
      bf16x2 v2 = *(const bf16x2*)(hb + (size_t)i2 * 128 + lane * 2);
      bf16x2 v3 = *(const bf16x2*)(hb + (size_t)i3 * 128 + lane * 2);
      bf16x2 v4 = *(const bf16x2*)(hb + (size_t)i4 * 128 + lane * 2);
      bf16x2 v5 = *(const bf16x2*)(hb + (size_t)i5 * 128 + lane * 2);
      bf16x2 v6 = *(const bf16x2*)(hb + (size_t)i6 * 128 + lane * 2);
      bf16x2 v7 = *(const bf16x2*)(hb + (size_t)i7 * 128 + lane * 2);
      s0.x += (float)v0[0]; s0.y += (float)v0[1];
      s1.x += (float)v1[0]; s1.y += (float)v1[1];
      s2.x += (float)v2[0]; s2.y += (float)v2[1];
      s3.x += (float)v3[0]; s3.y += (float)v3[1];
      s4.x += (float)v4[0]; s4.y += (float)v4[1];
      s5.x += (float)v5[0]; s5.y += (float)v5[1];
      s6.x += (float)v6[0]; s6.y += (float)v6[1];
      s7.x += (float)v7[0]; s7.y += (float)v7[1];
    }
    for (; j < dcap; j++) {
      int i0 = __builtin_amdgcn_readlane(idxv, j);
      bf16x2 vv = *(const bf16x2*)(hb + (size_t)i0 * 128 + lane * 2);
      s0.x += (float)vv[0]; s0.y += (float)vv[1];
    }
    for (int e = e0 + 64; e < e1; e++) {
      bf16x2 vv = *(const bf16x2*)(hb + (size_t)srcs[e] * 128 + lane * 2);
      s0.x += (float)vv[0]; s0.y += (float)vv[1];
    }
    ax += ((s0.x + s1.x) + (s2.x + s3.x)) + ((s4.x + s5.x) + (s6.x + s7.x));
    ay += ((s0.y + s1.y) + (s2.y + s3.y)) + ((s4.y + s5.y) + (s6.y + s7.y));
    bf16x2 z2 = {(__bf16)ax, (__bf16)ay};
    *(bf16x2*)(z + (size_t)row * 128 + lane * 2) = z2;
  }
}

// ---------------- dense MLP: u = relu(z@W1+b1)@W2+b2 + BN partials ----------
template <int CIN>
__global__ __launch_bounds__(256) void mlp_kernel(
    const __bf16* __restrict__ z, const __bf16* __restrict__ w1t,
    const float* __restrict__ b1, const __bf16* __restrict__ w2t,
    const float* __restrict__ b2, __bf16* __restrict__ u,
    float* __restrict__ bnstats) {
  constexpr int ZS = CIN + 8;
  constexpr int TS = HID + 8;
  constexpr int US = 132;
  constexpr int ZB = 64 * ZS * 2;
  constexpr int TB = 64 * TS * 2;
  constexpr int UB = 64 * US * 4;
  constexpr int SB = (ZB + TB) > UB ? (ZB + TB) : UB;
  __shared__ __align__(16) char smem[SB];
  __bf16* zt = (__bf16*)smem;
  __bf16* tt = (__bf16*)(smem + ZB);

  const int t = threadIdx.x;
  const int wave = t >> 6;
  const int lane = t & 63;
  const int l16 = lane & 15;
  const int quad = lane >> 4;
  const int rowbase = blockIdx.x * 64;
  const int nvalid = min(64, N_NODES - rowbase);

  // Phase A: coalesced global -> LDS staging of z (bf16x8 chunks)
  {
    constexpr int CH = CIN / 8;
    const bf16x8 zero8 = {};
    for (int f = t; f < 64 * CH; f += 256) {
      int r = f / CH, c = f - r * CH;
      int gr = rowbase + r;
      bf16x8 v = (gr < N_NODES) ? *(const bf16x8*)(z + (size_t)gr * CIN + c * 8) : zero8;
      *(bf16x8*)(zt + r * ZS + c * 8) = v;
    }
  }
  __syncthreads();

  const f32x4 zero4 = {0.f, 0.f, 0.f, 0.f};
  f32x4 acc[8];

  // Phase B: t = relu(z @ W1 + b1) -> LDS (bf16)
  {
#pragma unroll
    for (int ct = 0; ct < 8; ct++) acc[ct] = zero4;
    const __bf16* arow = zt + (wave * 16 + l16) * ZS + quad * 8;
#pragma unroll
    for (int ks = 0; ks < CIN / 32; ks++) {
      bf16x8 af = *(const bf16x8*)(arow + ks * 32);
#pragma unroll
      for (int ct = 0; ct < 8; ct++) {
        bf16x8 bfr = *(const bf16x8*)(w1t + (ct * 16 + l16) * CIN + ks * 32 + quad * 8);
        acc[ct] = __builtin_amdgcn_mfma_f32_16x16x32_bf16(af, bfr, acc[ct], 0, 0, 0);
      }
    }
#pragma unroll
    for (int ct = 0; ct < 8; ct++) {
      int col = ct * 16 + l16;
      float bias = b1[col];
#pragma unroll
      for (int r = 0; r < 4; r++) {
        float v = acc[ct][r] + bias;
        tt[(wave * 16 + quad * 4 + r) * TS + col] = (__bf16)(v > 0.f ? v : 0.f);
      }
    }
  }
  __syncthreads();

  // Phase C: u = t @ W2 + b2
  {
#pragma unroll
    for (int ct = 0; ct < 8; ct++) acc[ct] = zero4;
    const __bf16* arow = tt + (wave * 16 + l16) * TS + quad * 8;
#pragma unroll
    for (int ks = 0; ks < HID / 32; ks++) {
      bf16x8 af = *(const bf16x8*)(arow + ks * 32);
#pragma unroll
      for (int ct = 0; ct < 8; ct++) {
        bf16x8 bfr = *(const bf16x8*)(w2t + (ct * 16 + l16) * HID + ks * 32 + quad * 8);
        acc[ct] = __builtin_amdgcn_mfma_f32_16x16x32_bf16(af, bfr, acc[ct], 0, 0, 0);
      }
    }
  }
  __syncthreads();  // all tt reads done; reuse smem as fp32 u tile
  float* uo = (float*)smem;
#pragma unroll
  for (int ct = 0; ct < 8; ct++) {
    int col = ct * 16 + l16;
    float bias = b2[col];
#pragma unroll
    for (int r = 0; r < 4; r++) {
      uo[(wave * 16 + quad * 4 + r) * US + col] = acc[ct][r] + bias;
    }
  }
  __syncthreads();

  // coalesced bf16 global store of u + per-block BN partial sums (fp32)
  for (int f = t; f < 64 * 32; f += 256) {
    int r = f >> 5, c4 = f & 31;
    if (r < nvalid) {
      f32x4 v = *(const f32x4*)(uo + r * US + c4 * 4);
      bf16x4 o = {(__bf16)v[0], (__bf16)v[1], (__bf16)v[2], (__bf16)v[3]};
      *(bf16x4*)(u + (size_t)(rowbase + r) * HID + c4 * 4) = o;
    }
  }
  if (t < HID) {
    float s = 0.f, sq = 0.f;
    for (int r = 0; r < nvalid; r++) {
      float v = uo[r * US + t];
      s += v;
      sq += v * v;
    }
    atomicAdd(&bnstats[t], s);
    atomicAdd(&bnstats[HID + t], sq);
  }
}

// ---------------- BN finalize: a = g*rsqrt(var+eps), b = beta - mean*a ------
__global__ __launch_bounds__(128) void bn_finalize_kernel(const float* __restrict__ bnstats,
                                                          const float* __restrict__ gamma,
                                                          const float* __restrict__ beta,
                                                          float* __restrict__ bnab) {
  int t = threadIdx.x;
  const float invN = 1.f / (float)N_NODES;
  float mean = bnstats[t] * invN;
  float var = bnstats[HID + t] * invN - mean * mean;
  float a = gamma[t] * rsqrtf(var + BN_EPS);
  bnab[t] = a;
  bnab[HID + t] = beta[t] - mean * a;
}

// ---------------- BN apply + mean-pool accumulate (layer 2, bf16 in) --------
__global__ __launch_bounds__(128) void bn_apply_pool_kernel(const __bf16* __restrict__ u,
                                                            const float* __restrict__ bnab,
                                                            const int* __restrict__ batch,
                                                            float* __restrict__ pool) {
  int c = threadIdx.x;  // feature column
  int r0 = blockIdx.x * 64;
  if (r0 >= N_NODES) return;
  int rend = min(r0 + 64, N_NODES);
  float a = bnab[c], b = bnab[HID + c];
  float accv = 0.f;
  int curg = -1;
  for (int r = r0; r < rend; r++) {
    int g = batch[r];
    if (g != curg) {
      if (curg >= 0) atomicAdd(&pool[curg * HID + c], accv);
      curg = g;
      accv = 0.f;
    }
    float v = (float)u[(size_t)r * HID + c];
    v = v * a + b;
    accv += (v > 0.f ? v : 0.f);
  }
  if (curg >= 0) atomicAdd(&pool[curg * HID + c], accv);
}

// ---------------- per-graph node counts (batch is sorted) -------------------
__global__ __launch_bounds__(256) void count_kernel(const int* __restrict__ batch,
                                                    int* __restrict__ counts) {
  int t = blockIdx.x * 256 + threadIdx.x;
  int r0 = t * 64;
  if (r0 >= N_NODES) return;
  int rend = min(r0 + 64, N_NODES);
  int curg = batch[r0], cnt = 0;
  for (int r = r0; r < rend; r++) {
    int g = batch[r];
    if (g != curg) {
      atomicAdd(&counts[curg], cnt);
      curg = g;
      cnt = 1;
    } else {
      cnt++;
    }
  }
  atomicAdd(&counts[curg], cnt);
}

// ---------------- hg = pool/cnt; out = hg @ proj_w + proj_b -----------------
__global__ __launch_bounds__(128) void pool_proj_kernel(const float* __restrict__ pool,
                                                        const int* __restrict__ counts,
                                                        const float* __restrict__ pw,
                                                        const float* __restrict__ pb,
                                                        float* __restrict__ out) {
  int g = blockIdx.x;
  int c = threadIdx.x;
  __shared__ float hg[HID];
  float cnt = (float)max(counts[g], 1);
  hg[c] = pool[g * HID + c] / cnt;
  __syncthreads();
  float acc = pb[c];
#pragma unroll 8
  for (int k = 0; k < HID; k++) acc += hg[k] * pw[k * HID + c];
  out[g * HID + c] = acc;
}

// ============================================================================
extern "C" void kernel_launch(void* const* d_in, const int* in_sizes, int n_in,
                              void* d_out, int out_size, void* d_ws, size_t ws_size,
                              hipStream_t stream) {
  (void)in_sizes; (void)n_in; (void)out_size; (void)ws_size;
  const float* x = (const float*)d_in[0];
  const int* ei = (const int*)d_in[1];
  const int* batch = (const int*)d_in[2];
  const float* w1[3] = {(const float*)d_in[3], (const float*)d_in[9], (const float*)d_in[15]};
  const float* b1[3] = {(const float*)d_in[4], (const float*)d_in[10], (const float*)d_in[16]};
  const float* w2[3] = {(const float*)d_in[5], (const float*)d_in[11], (const float*)d_in[17]};
  const float* b2[3] = {(const float*)d_in[6], (const float*)d_in[12], (const float*)d_in[18]};
  const float* gm[3] = {(const float*)d_in[7], (const float*)d_in[13], (const float*)d_in[19]};
  const float* bt[3] = {(const float*)d_in[8], (const float*)d_in[14], (const float*)d_in[20]};
  const float* pw = (const float*)d_in[21];
  const float* pb = (const float*)d_in[22];
  float* out = (float*)d_out;

  // workspace carve
  char* ws = (char*)d_ws;
  __bf16* bufA = (__bf16*)ws;        ws += (size_t)N_NODES * HID * 2;   // 25.6 MB
  __bf16* bufB = (__bf16*)ws;        ws += (size_t)N_NODES * HID * 2;   // 25.6 MB
  __bf16* bufC = (__bf16*)ws;        ws += (size_t)N_NODES * HID * 2;   // 25.6 MB
  __bf16* z0 = (__bf16*)ws;          ws += (size_t)N_NODES * 64 * 2;    // 12.8 MB
  int* srcs = (int*)ws;              ws += (size_t)N_EDGES * 4;         // 6.4 MB
  int* epack = (int*)ws;             ws += (size_t)N_EDGES * 4;         // 6.4 MB
  int* starts = (int*)ws;            ws += (size_t)(N_NODES + 1) * 4;
  int* tcnt = (int*)ws;              ws += NT * 4;
  int* tstart = (int*)ws;            ws += (NT + 1) * 4;
  int* gcursor = (int*)ws;           ws += NT * 4;
  ws = (char*)(((uintptr_t)ws + 63) & ~(uintptr_t)63);
  __bf16* wt_all = (__bf16*)ws;      ws += 90112 * 2;
  ws = (char*)(((uintptr_t)ws + 63) & ~(uintptr_t)63);
  float* bnstats = (float*)ws;       ws += 256 * 4;
  float* bnab = (float*)ws;          ws += 256 * 4;
  float* pool = (float*)ws;          ws += N_GRAPHS * HID * 4;          // contiguous with counts
  int* counts = (int*)ws;            ws += N_GRAPHS * 4;

  __bf16* w1t0 = wt_all;
  __bf16* w2t0 = wt_all + 8192;
  __bf16* w1t1 = wt_all + 24576;
  __bf16* w2t1 = wt_all + 40960;
  __bf16* w1t2 = wt_all + 57344;
  __bf16* w2t2 = wt_all + 73728;

  const int mlp_blocks = (N_NODES + 63) / 64;  // 1563
  const int gat_blocks = (N_NODES + 3) / 4;    // 25000
  const int app_blocks = (N_NODES * (HID / 8) + 255) / 256;  // 6250

  // weight prep (bf16 transposed, one kernel)
  prep_all_kernel<<<(90112 + 255) / 256, 256, 0, stream>>>(
      w1[0], w2[0], w1[1], w2[1], w1[2], w2[2], wt_all);

  // CSR build: tile hist -> tile scan -> tile-bucket scatter -> per-tile sort
  hipMemsetAsync(tcnt, 0, NT * 4, stream);
  tile_hist_kernel<<<RB, 256, 0, stream>>>(ei, tcnt);
  tile_scan_kernel<<<1, 256, 0, stream>>>(tcnt, tstart, gcursor);
  reorder2_kernel<<<RB, 256, 0, stream>>>(ei, gcursor, epack);
  row_sort_kernel<<<NT, 256, 0, stream>>>(tstart, epack, starts, srcs);

  // zero pool + counts (contiguous), count nodes/graph
  hipMemsetAsync(pool, 0, (size_t)N_GRAPHS * HID * 4 + N_GRAPHS * 4, stream);
  count_kernel<<<((N_NODES + 63) / 64 + 255) / 256, 256, 0, stream>>>(batch, counts);

  // layer 0: gather(x fp32) -> z0; mlp64: z0 -> bufA (u0)
  hipMemsetAsync(bnstats, 0, 256 * 4, stream);
  gather_kernel<64, float><<<gat_blocks, 256, 0, stream>>>(x, starts, srcs, z0);
  mlp_kernel<64><<<mlp_blocks, 256, 0, stream>>>(z0, w1t0, b1[0], w2t0, b2[0], bufA, bnstats);
  bn_finalize_kernel<<<1, 128, 0, stream>>>(bnstats, gm[0], bt[0], bnab);

  // layer 1: h1 = relu(a*u0+b) -> bufB; gather -> bufC; mlp -> bufC in place
  hipMemsetAsync(bnstats, 0, 256 * 4, stream);
  h_apply_kernel<<<app_blocks, 256, 0, stream>>>(bufA, bnab, bufB);
  gather_kernel<128, __bf16><<<gat_blocks, 256, 0, stream>>>(bufB, starts, srcs, bufC);
  mlp_kernel<128><<<mlp_blocks, 256, 0, stream>>>(bufC, w1t1, b1[1], w2t1, b2[1], bufC, bnstats);
  bn_finalize_kernel<<<1, 128, 0, stream>>>(bnstats, gm[1], bt[1], bnab);

  // layer 2: h2 -> bufA; gather -> bufB; mlp -> bufB in place
  hipMemsetAsync(bnstats, 0, 256 * 4, stream);
  h_apply_kernel<<<app_blocks, 256, 0, stream>>>(bufC, bnab, bufA);
  gather_kernel<128, __bf16><<<gat_blocks, 256, 0, stream>>>(bufA, starts, srcs, bufB);
  mlp_kernel<128><<<mlp_blocks, 256, 0, stream>>>(bufB, w1t2, b1[2], w2t2, b2[2], bufB, bnstats);
  bn_finalize_kernel<<<1, 128, 0, stream>>>(bnstats, gm[2], bt[2], bnab);

  bn_apply_pool_kernel<<<mlp_blocks, 128, 0, stream>>>(bufB, bnab, batch, pool);

  pool_proj_kernel<<<N_GRAPHS, 128, 0, stream>>>(pool, counts, pw, pb, out);
}

// Round 8
// 623.327 us; speedup vs baseline: 11.4684x; 1.0197x over previous
//
#include <hip/hip_runtime.h>

#define N_NODES 100000
#define N_EDGES 1600000
#define N_GRAPHS 256
#define HID 128
#define BN_EPS 1e-5f

#define NT 1563        // ceil(N_NODES/64) tile buckets
#define EB 16384       // edges per reorder block
#define RB 98          // ceil(N_EDGES/EB)
#define MB 1563        // mlp blocks

typedef __bf16 bf16x8 __attribute__((ext_vector_type(8)));
typedef __bf16 bf16x4 __attribute__((ext_vector_type(4)));
typedef __bf16 bf16x2 __attribute__((ext_vector_type(2)));
typedef float f32x4 __attribute__((ext_vector_type(4)));

// ---------------- weight prep: all 6 weights -> one bf16 transposed buffer --
__global__ __launch_bounds__(256) void prep_all_kernel(
    const float* __restrict__ wa, const float* __restrict__ wb,
    const float* __restrict__ wc, const float* __restrict__ wd,
    const float* __restrict__ we, const float* __restrict__ wf,
    __bf16* __restrict__ wt) {
  int idx = blockIdx.x * 256 + threadIdx.x;
  if (idx >= 90112) return;
  const float* w;
  int K, local;
  if (idx < 8192) { w = wa; K = 64; local = idx; }
  else {
    int s = (idx - 8192) / 16384;
    local = (idx - 8192) - s * 16384;
    K = 128;
    w = (s == 0) ? wb : (s == 1) ? wc : (s == 2) ? wd : (s == 3) ? we : wf;
  }
  int n = local / K, k = local - n * K;
  wt[idx] = (__bf16)w[k * 128 + n];
}

// ---------------- CSR stage 1: tile-bucket histogram (LDS-staged) -----------
__global__ __launch_bounds__(256) void tile_hist_kernel(const int* __restrict__ ei,
                                                        int* __restrict__ tcnt) {
  __shared__ int hist[NT];
  int t = threadIdx.x;
  for (int i = t; i < NT; i += 256) hist[i] = 0;
  __syncthreads();
  int base = blockIdx.x * EB;
#pragma unroll 4
  for (int i = 0; i < EB / 256; i++) {
    int e = base + i * 256 + t;
    if (e < N_EDGES) atomicAdd(&hist[ei[N_EDGES + e] >> 6], 1);
  }
  __syncthreads();
  for (int i = t; i < NT; i += 256) {
    int h = hist[i];
    if (h) atomicAdd(&tcnt[i], h);
  }
}

// ---------------- CSR stage 2: scan 1563 tile counts ------------------------
__global__ __launch_bounds__(256) void tile_scan_kernel(const int* __restrict__ tcnt,
                                                        int* __restrict__ tstart,
                                                        int* __restrict__ gcursor) {
  __shared__ int ps[256];
  int t = threadIdx.x;
  const int CH = (NT + 255) / 256;  // 7
  int lo = t * CH, hi = min(lo + CH, NT);
  int s = 0;
  for (int i = lo; i < hi; i++) s += tcnt[i];
  ps[t] = s;
  __syncthreads();
  for (int off = 1; off < 256; off <<= 1) {
    int v = ps[t];
    int u = (t >= off) ? ps[t - off] : 0;
    __syncthreads();
    ps[t] = v + u;
    __syncthreads();
  }
  int base = (t == 0) ? 0 : ps[t - 1];
  for (int i = lo; i < hi; i++) {
    tstart[i] = base;
    gcursor[i] = base;
    base += tcnt[i];
  }
  if (t == 0) tstart[NT] = N_EDGES;
}

// ---------------- CSR stage 3: scatter into tile buckets (local writes) -----
__global__ __launch_bounds__(256) void reorder2_kernel(const int* __restrict__ ei,
                                                       int* __restrict__ gcursor,
                                                       int* __restrict__ epack) {
  __shared__ int hist[NT];
  int t = threadIdx.x;
  for (int i = t; i < NT; i += 256) hist[i] = 0;
  __syncthreads();
  int base = blockIdx.x * EB;
#pragma unroll 4
  for (int i = 0; i < EB / 256; i++) {
    int e = base + i * 256 + t;
    if (e < N_EDGES) atomicAdd(&hist[ei[N_EDGES + e] >> 6], 1);
  }
  __syncthreads();
  for (int i = t; i < NT; i += 256) {
    int h = hist[i];
    if (h) hist[i] = atomicAdd(&gcursor[i], h);
  }
  __syncthreads();
#pragma unroll 4
  for (int i = 0; i < EB / 256; i++) {
    int e = base + i * 256 + t;
    if (e < N_EDGES) {
      int d = ei[N_EDGES + e];
      int s = ei[e];
      int pos = atomicAdd(&hist[d >> 6], 1);
      epack[pos] = (s << 6) | (d & 63);
    }
  }
}

// ---------------- CSR stage 4: per-tile counting sort -> row CSR ------------
__global__ __launch_bounds__(256) void row_sort_kernel(const int* __restrict__ tstart,
                                                       const int* __restrict__ epack,
                                                       int* __restrict__ starts,
                                                       int* __restrict__ srcs) {
  __shared__ int cnt[64];
  __shared__ int rbase[65];
  __shared__ int rofs[64];
  int t = threadIdx.x, b = blockIdx.x;
  int ts = tstart[b], te = tstart[b + 1];
  if (t < 64) cnt[t] = 0;
  __syncthreads();
  for (int i = ts + t; i < te; i += 256) atomicAdd(&cnt[epack[i] & 63], 1);
  __syncthreads();
  if (t == 0) {
    int a = 0;
    for (int r = 0; r < 64; r++) { rbase[r] = a; a += cnt[r]; }
    rbase[64] = a;
  }
  __syncthreads();
  if (t < 64) rofs[t] = ts + rbase[t];
  if (t <= 64) {
    int gr = b * 64 + t;
    if (gr <= N_NODES) starts[gr] = ts + rbase[t];
  }
  __syncthreads();
  for (int i = ts + t; i < te; i += 256) {
    int p = epack[i];
    int pos = atomicAdd(&rofs[p & 63], 1);
    srcs[pos] = p >> 6;
  }
}

// ---------------- h = relu(a*u + b) elementwise, bf16 -> bf16 ---------------
__global__ __launch_bounds__(256) void h_apply_kernel(const __bf16* __restrict__ u,
                                                      const float* __restrict__ bnab,
                                                      __bf16* __restrict__ h) {
  int idx = blockIdx.x * 256 + threadIdx.x;  // chunk of 8 elems
  if (idx >= N_NODES * (HID / 8)) return;
  int c8 = idx & 15;  // chunk within row
  bf16x8 v = ((const bf16x8*)u)[idx];
  f32x4 a0 = ((const f32x4*)bnab)[c8 * 2];
  f32x4 a1 = ((const f32x4*)bnab)[c8 * 2 + 1];
  f32x4 b0 = ((const f32x4*)(bnab + HID))[c8 * 2];
  f32x4 b1 = ((const f32x4*)(bnab + HID))[c8 * 2 + 1];
  bf16x8 o;
#pragma unroll
  for (int k = 0; k < 4; k++) {
    o[k] = (__bf16)fmaxf(fmaf(a0[k], (float)v[k], b0[k]), 0.f);
    o[4 + k] = (__bf16)fmaxf(fmaf(a1[k], (float)v[4 + k], b1[k]), 0.f);
  }
  ((bf16x8*)h)[idx] = o;
}

// ---------------- gather: z[row] = h[row] + sum_{CSR[row]} h[src] -----------
template <int C, typename T>
__global__ __launch_bounds__(256) void gather_kernel(const T* __restrict__ h,
                                                     const int* __restrict__ starts,
                                                     const int* __restrict__ srcs,
                                                     __bf16* __restrict__ z) {
  const int lane = threadIdx.x & 63;
  const int row = blockIdx.x * 4 + (threadIdx.x >> 6);
  if (row >= N_NODES) return;
  int e0 = starts[row], e1 = starts[row + 1];
  int deg = e1 - e0;
  int idxv = srcs[min(e0 + lane, N_EDGES - 1)];
  int dcap = min(deg, 64);
  if constexpr (C == 64) {
    float acc = h[(size_t)row * 64 + lane];
    float s0 = 0.f, s1 = 0.f, s2 = 0.f, s3 = 0.f, s4 = 0.f, s5 = 0.f, s6 = 0.f, s7 = 0.f;
    int j = 0;
    for (; j + 7 < dcap; j += 8) {
      int i0 = __builtin_amdgcn_readlane(idxv, j);
      int i1 = __builtin_amdgcn_readlane(idxv, j + 1);
      int i2 = __builtin_amdgcn_readlane(idxv, j + 2);
      int i3 = __builtin_amdgcn_readlane(idxv, j + 3);
      int i4 = __builtin_amdgcn_readlane(idxv, j + 4);
      int i5 = __builtin_amdgcn_readlane(idxv, j + 5);
      int i6 = __builtin_amdgcn_readlane(idxv, j + 6);
      int i7 = __builtin_amdgcn_readlane(idxv, j + 7);
      float v0 = h[(size_t)i0 * 64 + lane];
      float v1 = h[(size_t)i1 * 64 + lane];
      float v2 = h[(size_t)i2 * 64 + lane];
      float v3 = h[(size_t)i3 * 64 + lane];
      float v4 = h[(size_t)i4 * 64 + lane];
      float v5 = h[(size_t)i5 * 64 + lane];
      float v6 = h[(size_t)i6 * 64 + lane];
      float v7 = h[(size_t)i7 * 64 + lane];
      s0 += v0; s1 += v1; s2 += v2; s3 += v3;
      s4 += v4; s5 += v5; s6 += v6; s7 += v7;
    }
    for (; j < dcap; j++) {
      int i0 = __builtin_amdgcn_readlane(idxv, j);
      s0 += h[(size_t)i0 * 64 + lane];
    }
    for (int e = e0 + 64; e < e1; e++) s0 += h[(size_t)srcs[e] * 64 + lane];
    acc += ((s0 + s1) + (s2 + s3)) + ((s4 + s5) + (s6 + s7));
    z[(size_t)row * 64 + lane] = (__bf16)acc;
  } else {
    const __bf16* hb = (const __bf16*)h;
    bf16x2 sv = *(const bf16x2*)(hb + (size_t)row * 128 + lane * 2);
    float ax = (float)sv[0], ay = (float)sv[1];
    float2 s0 = {0.f, 0.f}, s1 = {0.f, 0.f}, s2 = {0.f, 0.f}, s3 = {0.f, 0.f};
    float2 s4 = {0.f, 0.f}, s5 = {0.f, 0.f}, s6 = {0.f, 0.f}, s7 = {0.f, 0.f};
    int j = 0;
    for (; j + 7 < dcap; j += 8) {
      int i0 = __builtin_amdgcn_readlane(idxv, j);
      int i1 = __builtin_amdgcn_readlane(idxv, j + 1);
      int i2 = __builtin_amdgcn_readlane(idxv, j + 2);
      int i3 = __builtin_amdgcn_readlane(idxv, j + 3);
      int i4 = __builtin_amdgcn_readlane(idxv, j + 4);
      int i5 = __builtin_amdgcn_readlane(idxv, j + 5);
      int i6 = __builtin_amdgcn_readlane(idxv, j + 6);
      int i7 = __builtin_amdgcn_readlane(idxv, j + 7);
      bf16x2 v0 = *(const bf16x2*)(hb + (size_t)i0 * 128 + lane * 2);
      bf16x2 v1 = *(const bf16x2*)(hb + (size_t)i1 * 128 + lane * 2);
      bf16x2 v2 = *(const bf16x2*)(hb + (size_t)i2 * 128 + lane * 2);
      bf16x2 v3 = *(const bf16x2*)(hb + (size_t)i3 * 128 + lane * 2);
      bf16x2 v4 = *(const bf16x2*)(hb + (size_t)i4 * 128 + lane * 2);
      bf16x2 v5 = *(const bf16x2*)(hb + (size_t)i5 * 128 + lane * 2);
      bf16x2 v6 = *(const bf16x2*)(hb + (size_t)i6 * 128 + lane * 2);
      bf16x2 v7 = *(const bf16x2*)(hb + (size_t)i7 * 128 + lane * 2);
      s0.x += (float)v0[0]; s0.y += (float)v0[1];
      s1.x += (float)v1[0]; s1.y += (float)v1[1];
      s2.x += (float)v2[0]; s2.y += (float)v2[1];
      s3.x += (float)v3[0]; s3.y += (float)v3[1];
      s4.x += (float)v4[0]; s4.y += (float)v4[1];
      s5.x += (float)v5[0]; s5.y += (float)v5[1];
      s6.x += (float)v6[0]; s6.y += (float)v6[1];
      s7.x += (float)v7[0]; s7.y += (float)v7[1];
    }
    for (; j < dcap; j++) {
      int i0 = __builtin_amdgcn_readlane(idxv, j);
      bf16x2 vv = *(const bf16x2*)(hb + (size_t)i0 * 128 + lane * 2);
      s0.x += (float)vv[0]; s0.y += (float)vv[1];
    }
    for (int e = e0 + 64; e < e1; e++) {
      bf16x2 vv = *(const bf16x2*)(hb + (size_t)srcs[e] * 128 + lane * 2);
      s0.x += (float)vv[0]; s0.y += (float)vv[1];
    }
    ax += ((s0.x + s1.x) + (s2.x + s3.x)) + ((s4.x + s5.x) + (s6.x + s7.x));
    ay += ((s0.y + s1.y) + (s2.y + s3.y)) + ((s4.y + s5.y) + (s6.y + s7.y));
    bf16x2 z2 = {(__bf16)ax, (__bf16)ay};
    *(bf16x2*)(z + (size_t)row * 128 + lane * 2) = z2;
  }
}

// ---------------- dense MLP: u = relu(z@W1+b1)@W2+b2 + BN partials ----------
// BN partials go to part[block*256 + slot] (no global atomics).
template <int CIN>
__global__ __launch_bounds__(256) void mlp_kernel(
    const __bf16* __restrict__ z, const __bf16* __restrict__ w1t,
    const float* __restrict__ b1, const __bf16* __restrict__ w2t,
    const float* __restrict__ b2, __bf16* __restrict__ u,
    float* __restrict__ part) {
  constexpr int ZS = CIN + 8;
  constexpr int TS = HID + 8;
  constexpr int US = 132;
  constexpr int ZB = 64 * ZS * 2;
  constexpr int TB = 64 * TS * 2;
  constexpr int UB = 64 * US * 4;
  constexpr int SB = (ZB + TB) > UB ? (ZB + TB) : UB;
  __shared__ __align__(16) char smem[SB];
  __bf16* zt = (__bf16*)smem;
  __bf16* tt = (__bf16*)(smem + ZB);

  const int t = threadIdx.x;
  const int wave = t >> 6;
  const int lane = t & 63;
  const int l16 = lane & 15;
  const int quad = lane >> 4;
  const int rowbase = blockIdx.x * 64;
  const int nvalid = min(64, N_NODES - rowbase);

  // Phase A: coalesced global -> LDS staging of z (bf16x8 chunks)
  {
    constexpr int CH = CIN / 8;
    const bf16x8 zero8 = {};
    for (int f = t; f < 64 * CH; f += 256) {
      int r = f / CH, c = f - r * CH;
      int gr = rowbase + r;
      bf16x8 v = (gr < N_NODES) ? *(const bf16x8*)(z + (size_t)gr * CIN + c * 8) : zero8;
      *(bf16x8*)(zt + r * ZS + c * 8) = v;
    }
  }
  __syncthreads();

  const f32x4 zero4 = {0.f, 0.f, 0.f, 0.f};
  f32x4 acc[8];

  // Phase B: t = relu(z @ W1 + b1) -> LDS (bf16)
  {
#pragma unroll
    for (int ct = 0; ct < 8; ct++) acc[ct] = zero4;
    const __bf16* arow = zt + (wave * 16 + l16) * ZS + quad * 8;
#pragma unroll
    for (int ks = 0; ks < CIN / 32; ks++) {
      bf16x8 af = *(const bf16x8*)(arow + ks * 32);
#pragma unroll
      for (int ct = 0; ct < 8; ct++) {
        bf16x8 bfr = *(const bf16x8*)(w1t + (ct * 16 + l16) * CIN + ks * 32 + quad * 8);
        acc[ct] = __builtin_amdgcn_mfma_f32_16x16x32_bf16(af, bfr, acc[ct], 0, 0, 0);
      }
    }
#pragma unroll
    for (int ct = 0; ct < 8; ct++) {
      int col = ct * 16 + l16;
      float bias = b1[col];
#pragma unroll
      for (int r = 0; r < 4; r++) {
        float v = acc[ct][r] + bias;
        tt[(wave * 16 + quad * 4 + r) * TS + col] = (__bf16)(v > 0.f ? v : 0.f);
      }
    }
  }
  __syncthreads();

  // Phase C: u = t @ W2 + b2
  {
#pragma unroll
    for (int ct = 0; ct < 8; ct++) acc[ct] = zero4;
    const __bf16* arow = tt + (wave * 16 + l16) * TS + quad * 8;
#pragma unroll
    for (int ks = 0; ks < HID / 32; ks++) {
      bf16x8 af = *(const bf16x8*)(arow + ks * 32);
#pragma unroll
      for (int ct = 0; ct < 8; ct++) {
        bf16x8 bfr = *(const bf16x8*)(w2t + (ct * 16 + l16) * HID + ks * 32 + quad * 8);
        acc[ct] = __builtin_amdgcn_mfma_f32_16x16x32_bf16(af, bfr, acc[ct], 0, 0, 0);
      }
    }
  }
  __syncthreads();  // all tt reads done; reuse smem as fp32 u tile
  float* uo = (float*)smem;
#pragma unroll
  for (int ct = 0; ct < 8; ct++) {
    int col = ct * 16 + l16;
    float bias = b2[col];
#pragma unroll
    for (int r = 0; r < 4; r++) {
      uo[(wave * 16 + quad * 4 + r) * US + col] = acc[ct][r] + bias;
    }
  }
  __syncthreads();

  // coalesced bf16 global store of u + per-block BN partials (no atomics)
  for (int f = t; f < 64 * 32; f += 256) {
    int r = f >> 5, c4 = f & 31;
    if (r < nvalid) {
      f32x4 v = *(const f32x4*)(uo + r * US + c4 * 4);
      bf16x4 o = {(__bf16)v[0], (__bf16)v[1], (__bf16)v[2], (__bf16)v[3]};
      *(bf16x4*)(u + (size_t)(rowbase + r) * HID + c4 * 4) = o;
    }
  }
  if (t < HID) {
    float s = 0.f, sq = 0.f;
    for (int r = 0; r < nvalid; r++) {
      float v = uo[r * US + t];
      s += v;
      sq += v * v;
    }
    part[(size_t)blockIdx.x * 256 + t] = s;
    part[(size_t)blockIdx.x * 256 + HID + t] = sq;
  }
}

// ---------------- BN stats reduce + finalize (one block per column) ---------
__global__ __launch_bounds__(256) void bn_stats_kernel(const float* __restrict__ part,
                                                       const float* __restrict__ gamma,
                                                       const float* __restrict__ beta,
                                                       float* __restrict__ bnab) {
  __shared__ float ss[256], qq[256];
  int c = blockIdx.x;  // column 0..127
  int t = threadIdx.x;
  float s = 0.f, q = 0.f;
  for (int b = t; b < MB; b += 256) {
    s += part[(size_t)b * 256 + c];
    q += part[(size_t)b * 256 + HID + c];
  }
  ss[t] = s; qq[t] = q;
  __syncthreads();
  for (int off = 128; off > 0; off >>= 1) {
    if (t < off) { ss[t] += ss[t + off]; qq[t] += qq[t + off]; }
    __syncthreads();
  }
  if (t == 0) {
    const float invN = 1.f / (float)N_NODES;
    float mean = ss[0] * invN;
    float var = qq[0] * invN - mean * mean;
    float a = gamma[c] * rsqrtf(var + BN_EPS);
    bnab[c] = a;
    bnab[HID + c] = beta[c] - mean * a;
  }
}

// ---------------- BN apply + mean-pool accumulate (layer 2, bf16 in) --------
__global__ __launch_bounds__(128) void bn_apply_pool_kernel(const __bf16* __restrict__ u,
                                                            const float* __restrict__ bnab,
                                                            const int* __restrict__ batch,
                                                            float* __restrict__ pool) {
  int c = threadIdx.x;  // feature column
  int r0 = blockIdx.x * 64;
  if (r0 >= N_NODES) return;
  int rend = min(r0 + 64, N_NODES);
  float a = bnab[c], b = bnab[HID + c];
  float accv = 0.f;
  int curg = -1;
  for (int r = r0; r < rend; r++) {
    int g = batch[r];
    if (g != curg) {
      if (curg >= 0) atomicAdd(&pool[curg * HID + c], accv);
      curg = g;
      accv = 0.f;
    }
    float v = (float)u[(size_t)r * HID + c];
    v = v * a + b;
    accv += (v > 0.f ? v : 0.f);
  }
  if (curg >= 0) atomicAdd(&pool[curg * HID + c], accv);
}

// ---------------- per-graph node counts (batch is sorted) -------------------
__global__ __launch_bounds__(256) void count_kernel(const int* __restrict__ batch,
                                                    int* __restrict__ counts) {
  int t = blockIdx.x * 256 + threadIdx.x;
  int r0 = t * 64;
  if (r0 >= N_NODES) return;
  int rend = min(r0 + 64, N_NODES);
  int curg = batch[r0], cnt = 0;
  for (int r = r0; r < rend; r++) {
    int g = batch[r];
    if (g != curg) {
      atomicAdd(&counts[curg], cnt);
      curg = g;
      cnt = 1;
    } else {
      cnt++;
    }
  }
  atomicAdd(&counts[curg], cnt);
}

// ---------------- hg = pool/cnt; out = hg @ proj_w + proj_b -----------------
__global__ __launch_bounds__(128) void pool_proj_kernel(const float* __restrict__ pool,
                                                        const int* __restrict__ counts,
                                                        const float* __restrict__ pw,
                                                        const float* __restrict__ pb,
                                                        float* __restrict__ out) {
  int g = blockIdx.x;
  int c = threadIdx.x;
  __shared__ float hg[HID];
  float cnt = (float)max(counts[g], 1);
  hg[c] = pool[g * HID + c] / cnt;
  __syncthreads();
  float acc = pb[c];
#pragma unroll 8
  for (int k = 0; k < HID; k++) acc += hg[k] * pw[k * HID + c];
  out[g * HID + c] = acc;
}

// ============================================================================
extern "C" void kernel_launch(void* const* d_in, const int* in_sizes, int n_in,
                              void* d_out, int out_size, void* d_ws, size_t ws_size,
                              hipStream_t stream) {
  (void)in_sizes; (void)n_in; (void)out_size; (void)ws_size;
  const float* x = (const float*)d_in[0];
  const int* ei = (const int*)d_in[1];
  const int* batch = (const int*)d_in[2];
  const float* w1[3] = {(const float*)d_in[3], (const float*)d_in[9], (const float*)d_in[15]};
  const float* b1[3] = {(const float*)d_in[4], (const float*)d_in[10], (const float*)d_in[16]};
  const float* w2[3] = {(const float*)d_in[5], (const float*)d_in[11], (const float*)d_in[17]};
  const float* b2[3] = {(const float*)d_in[6], (const float*)d_in[12], (const float*)d_in[18]};
  const float* gm[3] = {(const float*)d_in[7], (const float*)d_in[13], (const float*)d_in[19]};
  const float* bt[3] = {(const float*)d_in[8], (const float*)d_in[14], (const float*)d_in[20]};
  const float* pw = (const float*)d_in[21];
  const float* pb = (const float*)d_in[22];
  float* out = (float*)d_out;

  // workspace carve
  char* ws = (char*)d_ws;
  __bf16* bufA = (__bf16*)ws;        ws += (size_t)N_NODES * HID * 2;   // 25.6 MB
  __bf16* bufB = (__bf16*)ws;        ws += (size_t)N_NODES * HID * 2;   // 25.6 MB
  __bf16* bufC = (__bf16*)ws;        ws += (size_t)N_NODES * HID * 2;   // 25.6 MB
  __bf16* z0 = (__bf16*)ws;          ws += (size_t)N_NODES * 64 * 2;    // 12.8 MB
  int* srcs = (int*)ws;              ws += (size_t)N_EDGES * 4;         // 6.4 MB
  int* epack = (int*)ws;             ws += (size_t)N_EDGES * 4;         // 6.4 MB
  int* starts = (int*)ws;            ws += (size_t)(N_NODES + 1) * 4;
  int* tcnt = (int*)ws;              ws += NT * 4;
  int* tstart = (int*)ws;            ws += (NT + 1) * 4;
  int* gcursor = (int*)ws;           ws += NT * 4;
  ws = (char*)(((uintptr_t)ws + 63) & ~(uintptr_t)63);
  float* part = (float*)ws;          ws += (size_t)MB * 256 * 4;        // 1.6 MB
  __bf16* wt_all = (__bf16*)ws;      ws += 90112 * 2;
  ws = (char*)(((uintptr_t)ws + 63) & ~(uintptr_t)63);
  float* bnab = (float*)ws;          ws += 256 * 4;
  float* pool = (float*)ws;          ws += N_GRAPHS * HID * 4;          // contiguous with counts
  int* counts = (int*)ws;            ws += N_GRAPHS * 4;

  __bf16* w1t0 = wt_all;
  __bf16* w2t0 = wt_all + 8192;
  __bf16* w1t1 = wt_all + 24576;
  __bf16* w2t1 = wt_all + 40960;
  __bf16* w1t2 = wt_all + 57344;
  __bf16* w2t2 = wt_all + 73728;

  const int mlp_blocks = MB;                   // 1563
  const int gat_blocks = (N_NODES + 3) / 4;    // 25000
  const int app_blocks = (N_NODES * (HID / 8) + 255) / 256;  // 6250

  // weight prep (bf16 transposed, one kernel)
  prep_all_kernel<<<(90112 + 255) / 256, 256, 0, stream>>>(
      w1[0], w2[0], w1[1], w2[1], w1[2], w2[2], wt_all);

  // CSR build: tile hist -> tile scan -> tile-bucket scatter -> per-tile sort
  hipMemsetAsync(tcnt, 0, NT * 4, stream);
  tile_hist_kernel<<<RB, 256, 0, stream>>>(ei, tcnt);
  tile_scan_kernel<<<1, 256, 0, stream>>>(tcnt, tstart, gcursor);
  reorder2_kernel<<<RB, 256, 0, stream>>>(ei, gcursor, epack);
  row_sort_kernel<<<NT, 256, 0, stream>>>(tstart, epack, starts, srcs);

  // zero pool + counts (contiguous), count nodes/graph
  hipMemsetAsync(pool, 0, (size_t)N_GRAPHS * HID * 4 + N_GRAPHS * 4, stream);
  count_kernel<<<((N_NODES + 63) / 64 + 255) / 256, 256, 0, stream>>>(batch, counts);

  // layer 0: gather(x fp32) -> z0; mlp64: z0 -> bufA (u0)
  gather_kernel<64, float><<<gat_blocks, 256, 0, stream>>>(x, starts, srcs, z0);
  mlp_kernel<64><<<mlp_blocks, 256, 0, stream>>>(z0, w1t0, b1[0], w2t0, b2[0], bufA, part);
  bn_stats_kernel<<<HID, 256, 0, stream>>>(part, gm[0], bt[0], bnab);

  // layer 1: h1 = relu(a*u0+b) -> bufB; gather -> bufC; mlp -> bufC in place
  h_apply_kernel<<<app_blocks, 256, 0, stream>>>(bufA, bnab, bufB);
  gather_kernel<128, __bf16><<<gat_blocks, 256, 0, stream>>>(bufB, starts, srcs, bufC);
  mlp_kernel<128><<<mlp_blocks, 256, 0, stream>>>(bufC, w1t1, b1[1], w2t1, b2[1], bufC, part);
  bn_stats_kernel<<<HID, 256, 0, stream>>>(part, gm[1], bt[1], bnab);

  // layer 2: h2 -> bufA; gather -> bufB; mlp -> bufB in place
  h_apply_kernel<<<app_blocks, 256, 0, stream>>>(bufC, bnab, bufA);
  gather_kernel<128, __bf16><<<gat_blocks, 256, 0, stream>>>(bufA, starts, srcs, bufB);
  mlp_kernel<128><<<mlp_blocks, 256, 0, stream>>>(bufB, w1t2, b1[2], w2t2, b2[2], bufB, part);
  bn_stats_kernel<<<HID, 256, 0, stream>>>(part, gm[2], bt[2], bnab);

  bn_apply_pool_kernel<<<mlp_blocks, 128, 0, stream>>>(bufB, bnab, batch, pool);

  pool_proj_kernel<<<N_GRAPHS, 128, 0, stream>>>(pool, counts, pw, pb, out);
}

// Round 9
// 604.592 us; speedup vs baseline: 11.8238x; 1.0310x over previous
//
#include <hip/hip_runtime.h>

#define N_NODES 100000
#define N_EDGES 1600000
#define N_GRAPHS 256
#define HID 128
#define BN_EPS 1e-5f

#define NT 1563        // ceil(N_NODES/64) tile buckets
#define EB 4096        // edges per reorder block
#define RB 391         // ceil(N_EDGES/EB)
#define MB 1563        // mlp blocks

typedef __bf16 bf16x8 __attribute__((ext_vector_type(8)));
typedef __bf16 bf16x4 __attribute__((ext_vector_type(4)));
typedef __bf16 bf16x2 __attribute__((ext_vector_type(2)));
typedef float f32x4 __attribute__((ext_vector_type(4)));

// ---------------- weight prep: all 6 weights -> one bf16 transposed buffer --
__global__ __launch_bounds__(256) void prep_all_kernel(
    const float* __restrict__ wa, const float* __restrict__ wb,
    const float* __restrict__ wc, const float* __restrict__ wd,
    const float* __restrict__ we, const float* __restrict__ wf,
    __bf16* __restrict__ wt) {
  int idx = blockIdx.x * 256 + threadIdx.x;
  if (idx >= 90112) return;
  const float* w;
  int K, local;
  if (idx < 8192) { w = wa; K = 64; local = idx; }
  else {
    int s = (idx - 8192) / 16384;
    local = (idx - 8192) - s * 16384;
    K = 128;
    w = (s == 0) ? wb : (s == 1) ? wc : (s == 2) ? wd : (s == 3) ? we : wf;
  }
  int n = local / K, k = local - n * K;
  wt[idx] = (__bf16)w[k * 128 + n];
}

// ---------------- x fp32 -> bf16 --------------------------------------------
__global__ __launch_bounds__(256) void x_convert_kernel(const float* __restrict__ x,
                                                        __bf16* __restrict__ xb) {
  int idx = blockIdx.x * 256 + threadIdx.x;  // chunk of 4
  if (idx >= N_NODES * 16) return;
  f32x4 v = ((const f32x4*)x)[idx];
  bf16x4 o = {(__bf16)v[0], (__bf16)v[1], (__bf16)v[2], (__bf16)v[3]};
  ((bf16x4*)xb)[idx] = o;
}

// ---------------- CSR stage 1: tile-bucket histogram (LDS-staged) -----------
__global__ __launch_bounds__(256) void tile_hist_kernel(const int* __restrict__ ei,
                                                        int* __restrict__ tcnt) {
  __shared__ int hist[NT];
  int t = threadIdx.x;
  for (int i = t; i < NT; i += 256) hist[i] = 0;
  __syncthreads();
  int base = blockIdx.x * EB;
#pragma unroll 4
  for (int i = 0; i < EB / 256; i++) {
    int e = base + i * 256 + t;
    if (e < N_EDGES) atomicAdd(&hist[ei[N_EDGES + e] >> 6], 1);
  }
  __syncthreads();
  for (int i = t; i < NT; i += 256) {
    int h = hist[i];
    if (h) atomicAdd(&tcnt[i], h);
  }
}

// ---------------- CSR stage 2: scan 1563 tile counts ------------------------
__global__ __launch_bounds__(256) void tile_scan_kernel(const int* __restrict__ tcnt,
                                                        int* __restrict__ tstart,
                                                        int* __restrict__ gcursor) {
  __shared__ int ps[256];
  int t = threadIdx.x;
  const int CH = (NT + 255) / 256;  // 7
  int lo = t * CH, hi = min(lo + CH, NT);
  int s = 0;
  for (int i = lo; i < hi; i++) s += tcnt[i];
  ps[t] = s;
  __syncthreads();
  for (int off = 1; off < 256; off <<= 1) {
    int v = ps[t];
    int u = (t >= off) ? ps[t - off] : 0;
    __syncthreads();
    ps[t] = v + u;
    __syncthreads();
  }
  int base = (t == 0) ? 0 : ps[t - 1];
  for (int i = lo; i < hi; i++) {
    tstart[i] = base;
    gcursor[i] = base;
    base += tcnt[i];
  }
  if (t == 0) tstart[NT] = N_EDGES;
}

// ---------------- CSR stage 3: scatter into tile buckets (local writes) -----
__global__ __launch_bounds__(256) void reorder2_kernel(const int* __restrict__ ei,
                                                       int* __restrict__ gcursor,
                                                       int* __restrict__ epack) {
  __shared__ int hist[NT];
  int t = threadIdx.x;
  for (int i = t; i < NT; i += 256) hist[i] = 0;
  __syncthreads();
  int base = blockIdx.x * EB;
#pragma unroll 4
  for (int i = 0; i < EB / 256; i++) {
    int e = base + i * 256 + t;
    if (e < N_EDGES) atomicAdd(&hist[ei[N_EDGES + e] >> 6], 1);
  }
  __syncthreads();
  for (int i = t; i < NT; i += 256) {
    int h = hist[i];
    if (h) hist[i] = atomicAdd(&gcursor[i], h);
  }
  __syncthreads();
#pragma unroll 4
  for (int i = 0; i < EB / 256; i++) {
    int e = base + i * 256 + t;
    if (e < N_EDGES) {
      int d = ei[N_EDGES + e];
      int s = ei[e];
      int pos = atomicAdd(&hist[d >> 6], 1);
      epack[pos] = (s << 6) | (d & 63);
    }
  }
}

// ---------------- CSR stage 4: per-tile counting sort -> row CSR ------------
__global__ __launch_bounds__(256) void row_sort_kernel(const int* __restrict__ tstart,
                                                       const int* __restrict__ epack,
                                                       int* __restrict__ starts,
                                                       int* __restrict__ srcs) {
  __shared__ int cnt[64];
  __shared__ int rbase[65];
  __shared__ int rofs[64];
  int t = threadIdx.x, b = blockIdx.x;
  int ts = tstart[b], te = tstart[b + 1];
  if (t < 64) cnt[t] = 0;
  __syncthreads();
  for (int i = ts + t; i < te; i += 256) atomicAdd(&cnt[epack[i] & 63], 1);
  __syncthreads();
  if (t == 0) {
    int a = 0;
    for (int r = 0; r < 64; r++) { rbase[r] = a; a += cnt[r]; }
    rbase[64] = a;
  }
  __syncthreads();
  if (t < 64) rofs[t] = ts + rbase[t];
  if (t <= 64) {
    int gr = b * 64 + t;
    if (gr <= N_NODES) starts[gr] = ts + rbase[t];
  }
  __syncthreads();
  for (int i = ts + t; i < te; i += 256) {
    int p = epack[i];
    int pos = atomicAdd(&rofs[p & 63], 1);
    srcs[pos] = p >> 6;
  }
}

// ---------------- h = relu(a*u + b) elementwise, bf16 -> bf16 ---------------
__global__ __launch_bounds__(256) void h_apply_kernel(const __bf16* __restrict__ u,
                                                      const float* __restrict__ bnab,
                                                      __bf16* __restrict__ h) {
  int idx = blockIdx.x * 256 + threadIdx.x;  // chunk of 8 elems
  if (idx >= N_NODES * (HID / 8)) return;
  int c8 = idx & 15;  // chunk within row
  bf16x8 v = ((const bf16x8*)u)[idx];
  f32x4 a0 = ((const f32x4*)bnab)[c8 * 2];
  f32x4 a1 = ((const f32x4*)bnab)[c8 * 2 + 1];
  f32x4 b0 = ((const f32x4*)(bnab + HID))[c8 * 2];
  f32x4 b1 = ((const f32x4*)(bnab + HID))[c8 * 2 + 1];
  bf16x8 o;
#pragma unroll
  for (int k = 0; k < 4; k++) {
    o[k] = (__bf16)fmaxf(fmaf(a0[k], (float)v[k], b0[k]), 0.f);
    o[4 + k] = (__bf16)fmaxf(fmaf(a1[k], (float)v[4 + k], b1[k]), 0.f);
  }
  ((bf16x8*)h)[idx] = o;
}

// ---------------- gather: z[row] = h[row] + sum_{CSR[row]} h[src] -----------
template <int C>
__global__ __launch_bounds__(256) void gather_kernel(const __bf16* __restrict__ h,
                                                     const int* __restrict__ starts,
                                                     const int* __restrict__ srcs,
                                                     __bf16* __restrict__ z) {
  const int lane = threadIdx.x & 63;
  const int row = blockIdx.x * 4 + (threadIdx.x >> 6);
  if (row >= N_NODES) return;
  int e0 = starts[row], e1 = starts[row + 1];
  int deg = e1 - e0;
  int idxv = srcs[min(e0 + lane, N_EDGES - 1)];
  int dcap = min(deg, 64);
  if constexpr (C == 64) {
    float acc = (float)h[(size_t)row * 64 + lane];
    float s0 = 0.f, s1 = 0.f, s2 = 0.f, s3 = 0.f, s4 = 0.f, s5 = 0.f, s6 = 0.f, s7 = 0.f;
    int j = 0;
    for (; j + 7 < dcap; j += 8) {
      int i0 = __builtin_amdgcn_readlane(idxv, j);
      int i1 = __builtin_amdgcn_readlane(idxv, j + 1);
      int i2 = __builtin_amdgcn_readlane(idxv, j + 2);
      int i3 = __builtin_amdgcn_readlane(idxv, j + 3);
      int i4 = __builtin_amdgcn_readlane(idxv, j + 4);
      int i5 = __builtin_amdgcn_readlane(idxv, j + 5);
      int i6 = __builtin_amdgcn_readlane(idxv, j + 6);
      int i7 = __builtin_amdgcn_readlane(idxv, j + 7);
      float v0 = (float)h[(size_t)i0 * 64 + lane];
      float v1 = (float)h[(size_t)i1 * 64 + lane];
      float v2 = (float)h[(size_t)i2 * 64 + lane];
      float v3 = (float)h[(size_t)i3 * 64 + lane];
      float v4 = (float)h[(size_t)i4 * 64 + lane];
      float v5 = (float)h[(size_t)i5 * 64 + lane];
      float v6 = (float)h[(size_t)i6 * 64 + lane];
      float v7 = (float)h[(size_t)i7 * 64 + lane];
      s0 += v0; s1 += v1; s2 += v2; s3 += v3;
      s4 += v4; s5 += v5; s6 += v6; s7 += v7;
    }
    for (; j < dcap; j++) {
      int i0 = __builtin_amdgcn_readlane(idxv, j);
      s0 += (float)h[(size_t)i0 * 64 + lane];
    }
    for (int e = e0 + 64; e < e1; e++) s0 += (float)h[(size_t)srcs[e] * 64 + lane];
    acc += ((s0 + s1) + (s2 + s3)) + ((s4 + s5) + (s6 + s7));
    z[(size_t)row * 64 + lane] = (__bf16)acc;
  } else {
    bf16x2 sv = *(const bf16x2*)(h + (size_t)row * 128 + lane * 2);
    float ax = (float)sv[0], ay = (float)sv[1];
    float2 s0 = {0.f, 0.f}, s1 = {0.f, 0.f}, s2 = {0.f, 0.f}, s3 = {0.f, 0.f};
    float2 s4 = {0.f, 0.f}, s5 = {0.f, 0.f}, s6 = {0.f, 0.f}, s7 = {0.f, 0.f};
    int j = 0;
    for (; j + 7 < dcap; j += 8) {
      int i0 = __builtin_amdgcn_readlane(idxv, j);
      int i1 = __builtin_amdgcn_readlane(idxv, j + 1);
      int i2 = __builtin_amdgcn_readlane(idxv, j + 2);
      int i3 = __builtin_amdgcn_readlane(idxv, j + 3);
      int i4 = __builtin_amdgcn_readlane(idxv, j + 4);
      int i5 = __builtin_amdgcn_readlane(idxv, j + 5);
      int i6 = __builtin_amdgcn_readlane(idxv, j + 6);
      int i7 = __builtin_amdgcn_readlane(idxv, j + 7);
      bf16x2 v0 = *(const bf16x2*)(h + (size_t)i0 * 128 + lane * 2);
      bf16x2 v1 = *(const bf16x2*)(h + (size_t)i1 * 128 + lane * 2);
      bf16x2 v2 = *(const bf16x2*)(h + (size_t)i2 * 128 + lane * 2);
      bf16x2 v3 = *(const bf16x2*)(h + (size_t)i3 * 128 + lane * 2);
      bf16x2 v4 = *(const bf16x2*)(h + (size_t)i4 * 128 + lane * 2);
      bf16x2 v5 = *(const bf16x2*)(h + (size_t)i5 * 128 + lane * 2);
      bf16x2 v6 = *(const bf16x2*)(h + (size_t)i6 * 128 + lane * 2);
      bf16x2 v7 = *(const bf16x2*)(h + (size_t)i7 * 128 + lane * 2);
      s0.x += (float)v0[0]; s0.y += (float)v0[1];
      s1.x += (float)v1[0]; s1.y += (float)v1[1];
      s2.x += (float)v2[0]; s2.y += (float)v2[1];
      s3.x += (float)v3[0]; s3.y += (float)v3[1];
      s4.x += (float)v4[0]; s4.y += (float)v4[1];
      s5.x += (float)v5[0]; s5.y += (float)v5[1];
      s6.x += (float)v6[0]; s6.y += (float)v6[1];
      s7.x += (float)v7[0]; s7.y += (float)v7[1];
    }
    for (; j < dcap; j++) {
      int i0 = __builtin_amdgcn_readlane(idxv, j);
      bf16x2 vv = *(const bf16x2*)(h + (size_t)i0 * 128 + lane * 2);
      s0.x += (float)vv[0]; s0.y += (float)vv[1];
    }
    for (int e = e0 + 64; e < e1; e++) {
      bf16x2 vv = *(const bf16x2*)(h + (size_t)srcs[e] * 128 + lane * 2);
      s0.x += (float)vv[0]; s0.y += (float)vv[1];
    }
    ax += ((s0.x + s1.x) + (s2.x + s3.x)) + ((s4.x + s5.x) + (s6.x + s7.x));
    ay += ((s0.y + s1.y) + (s2.y + s3.y)) + ((s4.y + s5.y) + (s6.y + s7.y));
    bf16x2 z2 = {(__bf16)ax, (__bf16)ay};
    *(bf16x2*)(z + (size_t)row * 128 + lane * 2) = z2;
  }
}

// ---------------- dense MLP: u = relu(z@W1+b1)@W2+b2 + BN partials ----------
template <int CIN>
__global__ __launch_bounds__(256) void mlp_kernel(
    const __bf16* __restrict__ z, const __bf16* __restrict__ w1t,
    const float* __restrict__ b1, const __bf16* __restrict__ w2t,
    const float* __restrict__ b2, __bf16* __restrict__ u,
    float* __restrict__ part) {
  constexpr int ZS = CIN + 8;
  constexpr int TS = HID + 8;
  constexpr int US = 132;
  constexpr int ZB = 64 * ZS * 2;
  constexpr int TB = 64 * TS * 2;
  constexpr int UB = 64 * US * 4;
  constexpr int SB = (ZB + TB) > UB ? (ZB + TB) : UB;
  __shared__ __align__(16) char smem[SB];
  __bf16* zt = (__bf16*)smem;
  __bf16* tt = (__bf16*)(smem + ZB);

  const int t = threadIdx.x;
  const int wave = t >> 6;
  const int lane = t & 63;
  const int l16 = lane & 15;
  const int quad = lane >> 4;
  const int rowbase = blockIdx.x * 64;
  const int nvalid = min(64, N_NODES - rowbase);

  // Phase A: coalesced global -> LDS staging of z (bf16x8 chunks)
  {
    constexpr int CH = CIN / 8;
    const bf16x8 zero8 = {};
    for (int f = t; f < 64 * CH; f += 256) {
      int r = f / CH, c = f - r * CH;
      int gr = rowbase + r;
      bf16x8 v = (gr < N_NODES) ? *(const bf16x8*)(z + (size_t)gr * CIN + c * 8) : zero8;
      *(bf16x8*)(zt + r * ZS + c * 8) = v;
    }
  }
  __syncthreads();

  const f32x4 zero4 = {0.f, 0.f, 0.f, 0.f};
  f32x4 acc[8];

  // Phase B: t = relu(z @ W1 + b1) -> LDS (bf16)
  {
#pragma unroll
    for (int ct = 0; ct < 8; ct++) acc[ct] = zero4;
    const __bf16* arow = zt + (wave * 16 + l16) * ZS + quad * 8;
#pragma unroll
    for (int ks = 0; ks < CIN / 32; ks++) {
      bf16x8 af = *(const bf16x8*)(arow + ks * 32);
#pragma unroll
      for (int ct = 0; ct < 8; ct++) {
        bf16x8 bfr = *(const bf16x8*)(w1t + (ct * 16 + l16) * CIN + ks * 32 + quad * 8);
        acc[ct] = __builtin_amdgcn_mfma_f32_16x16x32_bf16(af, bfr, acc[ct], 0, 0, 0);
      }
    }
#pragma unroll
    for (int ct = 0; ct < 8; ct++) {
      int col = ct * 16 + l16;
      float bias = b1[col];
#pragma unroll
      for (int r = 0; r < 4; r++) {
        float v = acc[ct][r] + bias;
        tt[(wave * 16 + quad * 4 + r) * TS + col] = (__bf16)(v > 0.f ? v : 0.f);
      }
    }
  }
  __syncthreads();

  // Phase C: u = t @ W2 + b2
  {
#pragma unroll
    for (int ct = 0; ct < 8; ct++) acc[ct] = zero4;
    const __bf16* arow = tt + (wave * 16 + l16) * TS + quad * 8;
#pragma unroll
    for (int ks = 0; ks < HID / 32; ks++) {
      bf16x8 af = *(const bf16x8*)(arow + ks * 32);
#pragma unroll
      for (int ct = 0; ct < 8; ct++) {
        bf16x8 bfr = *(const bf16x8*)(w2t + (ct * 16 + l16) * HID + ks * 32 + quad * 8);
        acc[ct] = __builtin_amdgcn_mfma_f32_16x16x32_bf16(af, bfr, acc[ct], 0, 0, 0);
      }
    }
  }
  __syncthreads();  // all tt reads done; reuse smem as fp32 u tile
  float* uo = (float*)smem;
#pragma unroll
  for (int ct = 0; ct < 8; ct++) {
    int col = ct * 16 + l16;
    float bias = b2[col];
#pragma unroll
    for (int r = 0; r < 4; r++) {
      uo[(wave * 16 + quad * 4 + r) * US + col] = acc[ct][r] + bias;
    }
  }
  __syncthreads();

  // coalesced bf16 global store of u + per-block BN partials (no atomics)
  for (int f = t; f < 64 * 32; f += 256) {
    int r = f >> 5, c4 = f & 31;
    if (r < nvalid) {
      f32x4 v = *(const f32x4*)(uo + r * US + c4 * 4);
      bf16x4 o = {(__bf16)v[0], (__bf16)v[1], (__bf16)v[2], (__bf16)v[3]};
      *(bf16x4*)(u + (size_t)(rowbase + r) * HID + c4 * 4) = o;
    }
  }
  if (t < HID) {
    float s = 0.f, sq = 0.f;
    for (int r = 0; r < nvalid; r++) {
      float v = uo[r * US + t];
      s += v;
      sq += v * v;
    }
    part[(size_t)blockIdx.x * 256 + t] = s;
    part[(size_t)blockIdx.x * 256 + HID + t] = sq;
  }
}

// ---------------- BN stats reduce + finalize (one block per column) ---------
__global__ __launch_bounds__(256) void bn_stats_kernel(const float* __restrict__ part,
                                                       const float* __restrict__ gamma,
                                                       const float* __restrict__ beta,
                                                       float* __restrict__ bnab) {
  __shared__ float ss[256], qq[256];
  int c = blockIdx.x;  // column 0..127
  int t = threadIdx.x;
  float s = 0.f, q = 0.f;
  for (int b = t; b < MB; b += 256) {
    s += part[(size_t)b * 256 + c];
    q += part[(size_t)b * 256 + HID + c];
  }
  ss[t] = s; qq[t] = q;
  __syncthreads();
  for (int off = 128; off > 0; off >>= 1) {
    if (t < off) { ss[t] += ss[t + off]; qq[t] += qq[t + off]; }
    __syncthreads();
  }
  if (t == 0) {
    const float invN = 1.f / (float)N_NODES;
    float mean = ss[0] * invN;
    float var = qq[0] * invN - mean * mean;
    float a = gamma[c] * rsqrtf(var + BN_EPS);
    bnab[c] = a;
    bnab[HID + c] = beta[c] - mean * a;
  }
}

// ---------------- BN apply + mean-pool accumulate (layer 2, bf16 in) --------
__global__ __launch_bounds__(128) void bn_apply_pool_kernel(const __bf16* __restrict__ u,
                                                            const float* __restrict__ bnab,
                                                            const int* __restrict__ batch,
                                                            float* __restrict__ pool) {
  int c = threadIdx.x;  // feature column
  int r0 = blockIdx.x * 64;
  if (r0 >= N_NODES) return;
  int rend = min(r0 + 64, N_NODES);
  float a = bnab[c], b = bnab[HID + c];
  float accv = 0.f;
  int curg = -1;
  for (int r = r0; r < rend; r++) {
    int g = batch[r];
    if (g != curg) {
      if (curg >= 0) atomicAdd(&pool[curg * HID + c], accv);
      curg = g;
      accv = 0.f;
    }
    float v = (float)u[(size_t)r * HID + c];
    v = v * a + b;
    accv += (v > 0.f ? v : 0.f);
  }
  if (curg >= 0) atomicAdd(&pool[curg * HID + c], accv);
}

// ---------------- per-graph node counts (batch is sorted) -------------------
__global__ __launch_bounds__(256) void count_kernel(const int* __restrict__ batch,
                                                    int* __restrict__ counts) {
  int t = blockIdx.x * 256 + threadIdx.x;
  int r0 = t * 64;
  if (r0 >= N_NODES) return;
  int rend = min(r0 + 64, N_NODES);
  int curg = batch[r0], cnt = 0;
  for (int r = r0; r < rend; r++) {
    int g = batch[r];
    if (g != curg) {
      atomicAdd(&counts[curg], cnt);
      curg = g;
      cnt = 1;
    } else {
      cnt++;
    }
  }
  atomicAdd(&counts[curg], cnt);
}

// ---------------- hg = pool/cnt; out = hg @ proj_w + proj_b -----------------
__global__ __launch_bounds__(128) void pool_proj_kernel(const float* __restrict__ pool,
                                                        const int* __restrict__ counts,
                                                        const float* __restrict__ pw,
                                                        const float* __restrict__ pb,
                                                        float* __restrict__ out) {
  int g = blockIdx.x;
  int c = threadIdx.x;
  __shared__ float hg[HID];
  float cnt = (float)max(counts[g], 1);
  hg[c] = pool[g * HID + c] / cnt;
  __syncthreads();
  float acc = pb[c];
#pragma unroll 8
  for (int k = 0; k < HID; k++) acc += hg[k] * pw[k * HID + c];
  out[g * HID + c] = acc;
}

// ============================================================================
extern "C" void kernel_launch(void* const* d_in, const int* in_sizes, int n_in,
                              void* d_out, int out_size, void* d_ws, size_t ws_size,
                              hipStream_t stream) {
  (void)in_sizes; (void)n_in; (void)out_size; (void)ws_size;
  const float* x = (const float*)d_in[0];
  const int* ei = (const int*)d_in[1];
  const int* batch = (const int*)d_in[2];
  const float* w1[3] = {(const float*)d_in[3], (const float*)d_in[9], (const float*)d_in[15]};
  const float* b1[3] = {(const float*)d_in[4], (const float*)d_in[10], (const float*)d_in[16]};
  const float* w2[3] = {(const float*)d_in[5], (const float*)d_in[11], (const float*)d_in[17]};
  const float* b2[3] = {(const float*)d_in[6], (const float*)d_in[12], (const float*)d_in[18]};
  const float* gm[3] = {(const float*)d_in[7], (const float*)d_in[13], (const float*)d_in[19]};
  const float* bt[3] = {(const float*)d_in[8], (const float*)d_in[14], (const float*)d_in[20]};
  const float* pw = (const float*)d_in[21];
  const float* pb = (const float*)d_in[22];
  float* out = (float*)d_out;

  // workspace carve
  char* ws = (char*)d_ws;
  __bf16* bufA = (__bf16*)ws;        ws += (size_t)N_NODES * HID * 2;   // 25.6 MB
  __bf16* bufB = (__bf16*)ws;        ws += (size_t)N_NODES * HID * 2;   // 25.6 MB
  __bf16* bufC = (__bf16*)ws;        ws += (size_t)N_NODES * HID * 2;   // 25.6 MB
  __bf16* z0 = (__bf16*)ws;          ws += (size_t)N_NODES * 64 * 2;    // 12.8 MB
  __bf16* xb = (__bf16*)ws;          ws += (size_t)N_NODES * 64 * 2;    // 12.8 MB
  int* srcs = (int*)ws;              ws += (size_t)N_EDGES * 4;         // 6.4 MB
  int* epack = (int*)ws;             ws += (size_t)N_EDGES * 4;         // 6.4 MB
  int* starts = (int*)ws;            ws += (size_t)(N_NODES + 1) * 4;
  int* tcnt = (int*)ws;              ws += NT * 4;
  int* tstart = (int*)ws;            ws += (NT + 1) * 4;
  int* gcursor = (int*)ws;           ws += NT * 4;
  ws = (char*)(((uintptr_t)ws + 63) & ~(uintptr_t)63);
  float* part = (float*)ws;          ws += (size_t)MB * 256 * 4;        // 1.6 MB
  __bf16* wt_all = (__bf16*)ws;      ws += 90112 * 2;
  ws = (char*)(((uintptr_t)ws + 63) & ~(uintptr_t)63);
  float* bnab = (float*)ws;          ws += 256 * 4;
  float* pool = (float*)ws;          ws += N_GRAPHS * HID * 4;          // contiguous with counts
  int* counts = (int*)ws;            ws += N_GRAPHS * 4;

  __bf16* w1t0 = wt_all;
  __bf16* w2t0 = wt_all + 8192;
  __bf16* w1t1 = wt_all + 24576;
  __bf16* w2t1 = wt_all + 40960;
  __bf16* w1t2 = wt_all + 57344;
  __bf16* w2t2 = wt_all + 73728;

  const int mlp_blocks = MB;                   // 1563
  const int gat_blocks = (N_NODES + 3) / 4;    // 25000
  const int app_blocks = (N_NODES * (HID / 8) + 255) / 256;  // 6250

  // weight prep + x->bf16
  prep_all_kernel<<<(90112 + 255) / 256, 256, 0, stream>>>(
      w1[0], w2[0], w1[1], w2[1], w1[2], w2[2], wt_all);
  x_convert_kernel<<<(N_NODES * 16 + 255) / 256, 256, 0, stream>>>(x, xb);

  // CSR build: tile hist -> tile scan -> tile-bucket scatter -> per-tile sort
  hipMemsetAsync(tcnt, 0, NT * 4, stream);
  tile_hist_kernel<<<RB, 256, 0, stream>>>(ei, tcnt);
  tile_scan_kernel<<<1, 256, 0, stream>>>(tcnt, tstart, gcursor);
  reorder2_kernel<<<RB, 256, 0, stream>>>(ei, gcursor, epack);
  row_sort_kernel<<<NT, 256, 0, stream>>>(tstart, epack, starts, srcs);

  // zero pool + counts (contiguous), count nodes/graph
  hipMemsetAsync(pool, 0, (size_t)N_GRAPHS * HID * 4 + N_GRAPHS * 4, stream);
  count_kernel<<<((N_NODES + 63) / 64 + 255) / 256, 256, 0, stream>>>(batch, counts);

  // layer 0: gather(xb bf16) -> z0; mlp64: z0 -> bufA (u0)
  gather_kernel<64><<<gat_blocks, 256, 0, stream>>>(xb, starts, srcs, z0);
  mlp_kernel<64><<<mlp_blocks, 256, 0, stream>>>(z0, w1t0, b1[0], w2t0, b2[0], bufA, part);
  bn_stats_kernel<<<HID, 256, 0, stream>>>(part, gm[0], bt[0], bnab);

  // layer 1: h1 = relu(a*u0+b) -> bufB; gather -> bufC; mlp -> bufC in place
  h_apply_kernel<<<app_blocks, 256, 0, stream>>>(bufA, bnab, bufB);
  gather_kernel<128><<<gat_blocks, 256, 0, stream>>>(bufB, starts, srcs, bufC);
  mlp_kernel<128><<<mlp_blocks, 256, 0, stream>>>(bufC, w1t1, b1[1], w2t1, b2[1], bufC, part);
  bn_stats_kernel<<<HID, 256, 0, stream>>>(part, gm[1], bt[1], bnab);

  // layer 2: h2 -> bufA; gather -> bufB; mlp -> bufB in place
  h_apply_kernel<<<app_blocks, 256, 0, stream>>>(bufC, bnab, bufA);
  gather_kernel<128><<<gat_blocks, 256, 0, stream>>>(bufA, starts, srcs, bufB);
  mlp_kernel<128><<<mlp_blocks, 256, 0, stream>>>(bufB, w1t2, b1[2], w2t2, b2[2], bufB, part);
  bn_stats_kernel<<<HID, 256, 0, stream>>>(part, gm[2], bt[2], bnab);

  bn_apply_pool_kernel<<<mlp_blocks, 128, 0, stream>>>(bufB, bnab, batch, pool);

  pool_proj_kernel<<<N_GRAPHS, 128, 0, stream>>>(pool, counts, pw, pb, out);
}